// Round 4
// baseline (4066.508 us; speedup 1.0000x reference)
//
#include <hip/hip_runtime.h>
#include <hip/hip_bf16.h>
#include <math.h>

// ---------------- problem constants ----------------
#define N_BATCH 2
#define HH 50
#define WW 84
#define NPIX (HH*WW)           // 4200
#define KA (NPIX*9)            // 37800
#define N_PRE 6000
#define N_POST 300
#define NMS_T 0.7f
#define NEGV (-1e9f)
#define NWORDS 94              // ceil(6000/64)

// d_out offsets (floats)
#define OFF_LOCS   0
#define OFF_SCORES (N_BATCH*KA*4)                  // 302400
#define OFF_ROIS   (OFF_SCORES + N_BATCH*KA*2)     // 453600
#define OFF_RIDX   (OFF_ROIS + N_BATCH*N_POST*4)   // 456000
#define OFF_ANCH   (OFF_RIDX + N_BATCH*N_POST)     // 456600

// ws offsets (bytes), all 16B aligned
#define WS_HID    0ull
#define WS_FG     17203200ull
#define WS_ROI    17505600ull
#define WS_ITEMS  18715200ull   // items; ALSO wT (9.44MB) during conv phase (reused)
#define WS_SITEMS 19320000ull
#define WS_SBOX   19416000ull
#define WS_MASK   19608000ull
#define WS_DIAG   28632000ull   // 2*6000*8 = 96000 B
#define WS_WT     WS_ITEMS      // wT[4608][512] f32, dead before k_prep writes items

typedef unsigned long long u64;
typedef unsigned u32;

// ---------------- anchors ----------------
__global__ void k_anchor(float* __restrict__ out) {
  int k = blockIdx.x * 256 + threadIdx.x;
  if (k >= KA) return;
  int a = k % 9; int pj = k / 9; int j = pj % WW; int i = pj / WW;
  int ri = a / 3, si = a % 3;
  double ratio = (ri == 0) ? 0.5 : ((ri == 1) ? 1.0 : 2.0);
  double scale = (si == 0) ? 8.0 : ((si == 1) ? 16.0 : 32.0);
  double h = 16.0 * scale * sqrt(ratio);
  double w = 16.0 * scale * sqrt(1.0 / ratio);
  float y1 = (float)(8.0 - h * 0.5), x1 = (float)(8.0 - w * 0.5);
  float y2 = (float)(8.0 + h * 0.5), x2 = (float)(8.0 + w * 0.5);
  float sy = (float)(i * 16), sx = (float)(j * 16);
  ((float4*)out)[OFF_ANCH / 4 + k] = make_float4(sy + y1, sx + x1, sy + y2, sx + x2);
}

// ---------------- weight transpose: wT[ict][oc] = w[oc][ict] ----------------
// tiles of 72 ict x 32 oc via LDS
__global__ __launch_bounds__(256) void k_wt(const float* __restrict__ w,
    float* __restrict__ wT) {
  const int t0 = blockIdx.x * 72;   // 0..4536
  const int oc0 = blockIdx.y * 32;  // 0..480
  const int tid = threadIdx.x;
  __shared__ float ls[32][73];
  for (int i = tid; i < 32 * 72; i += 256) {
    int ol = i / 72, tl = i % 72;
    ls[ol][tl] = w[(size_t)(oc0 + ol) * 4608 + t0 + tl];
  }
  __syncthreads();
  for (int i = tid; i < 32 * 72; i += 256) {
    int tl = i >> 5, ol = i & 31;
    wT[(size_t)(t0 + tl) * 512 + oc0 + ol] = ls[ol][tl];
  }
}

// ---------------- conv1 3x3 512->512 + relu ----------------
// thread = 1 pixel, acc over 16 oc. Weights via wave-uniform loads (SGPR
// operand path -> zero LDS/VALU cost). Per ic: 9 ds_read_b32 (3x3 window,
// one base + imm offsets) vs 288 FMA cycles -> FMA-issue-bound.
#define IC_T 8
__global__ __launch_bounds__(256, 4) void k_conv1(const float* __restrict__ x,
    const float* __restrict__ wT, const float* __restrict__ bias,
    float* __restrict__ hid) {
  const int ocb = blockIdx.x;   // 0..31 (16 oc each)
  const int pxb = blockIdx.y;   // 0..16 (256 px each)
  const int n   = blockIdx.z;   // 0..1
  const int tid = threadIdx.x;
  const int P0  = pxb * 256;
  const int p   = P0 + tid;            // 0..4351
  const bool act = p < NPIX;
  const int r = p / 84, c = p - r * 84;
  const int row0 = P0 / 84;
  __shared__ float lx[IC_T * 6 * 88];  // [ic][row0-1..row0+4][col-1(+88)] 16.5KB

  const float* xg = x + (size_t)n * 512 * NPIX;

  // staging map: 4224 floats, idx = tid + k*256
  int goff[17];
#pragma unroll
  for (int k = 0; k < 17; k++) {
    int idx = tid + k * 256;
    int ic = idx / 528; int rem = idx - ic * 528;
    int L = rem / 88; int col = rem - L * 88;
    int gr = row0 - 1 + L; int gc = col - 1;
    bool v = (idx < 4224) && ((unsigned)gr < 50u) && ((unsigned)gc < 84u);
    goff[k] = v ? (ic * NPIX + gr * 84 + gc) : -1;
  }

  float acc[16];
#pragma unroll
  for (int o = 0; o < 16; o++) acc[o] = 0.f;

  const float* base = &lx[(r - row0) * 88 + c];  // window reads = base + imm

  float xs[17];
  // prologue: stage tile 0
#pragma unroll
  for (int k = 0; k < 17; k++) xs[k] = (goff[k] >= 0) ? xg[goff[k]] : 0.f;
#pragma unroll
  for (int k = 0; k < 17; k++) {
    int idx = tid + k * 256;
    if (idx < 4224) lx[idx] = xs[k];
  }
  __syncthreads();

  for (int t = 0; t < 512 / IC_T; t++) {
    // issue next tile's global loads (hidden under compute)
    if (t < 512 / IC_T - 1) {
      int adv = (t + 1) * IC_T * NPIX;
#pragma unroll
      for (int k = 0; k < 17; k++) xs[k] = (goff[k] >= 0) ? xg[goff[k] + adv] : 0.f;
    }
    // compute current tile
    const float* wpt = wT + (size_t)(t * IC_T) * 9 * 512 + ocb * 16;
#pragma unroll
    for (int ic = 0; ic < IC_T; ic++) {
#pragma unroll
      for (int ky = 0; ky < 3; ky++) {
#pragma unroll
        for (int kx = 0; kx < 3; kx++) {
          float xv = base[ic * 528 + ky * 88 + kx];
          const float* wp = wpt + (size_t)(ic * 9 + ky * 3 + kx) * 512;
#pragma unroll
          for (int o = 0; o < 16; o++) acc[o] = fmaf(wp[o], xv, acc[o]);
        }
      }
    }
    __syncthreads();
    if (t < 512 / IC_T - 1) {
#pragma unroll
      for (int k = 0; k < 17; k++) {
        int idx = tid + k * 256;
        if (idx < 4224) lx[idx] = xs[k];
      }
      __syncthreads();
    }
  }

  if (act) {
#pragma unroll
    for (int o = 0; o < 16; o++) {
      float v = acc[o] + bias[ocb * 16 + o];
      hid[(size_t)(n * 512 + ocb * 16 + o) * NPIX + p] = v > 0.f ? v : 0.f;
    }
  }
}

// ---------------- 1x1 heads (18 score + 36 loc) + fg softmax ----------------
__global__ __launch_bounds__(256) void k_head(const float* __restrict__ hid,
    const float* __restrict__ sw, const float* __restrict__ sb,
    const float* __restrict__ lww, const float* __restrict__ lb,
    float* __restrict__ out, float* __restrict__ fg) {
  const int tid = threadIdx.x;
  const int P0 = blockIdx.x * 256;
  const int P = P0 + tid;
  __shared__ float xt[32 * 256];
  __shared__ float wt[32 * 56];
  float acc[54];
#pragma unroll
  for (int o = 0; o < 54; o++) acc[o] = 0.f;

  for (int c0 = 0; c0 < 512; c0 += 32) {
    for (int i = tid; i < 32 * 256; i += 256) {
      int c = i >> 8; int lp = i & 255;
      int PP = P0 + lp;
      float v = 0.f;
      if (PP < N_BATCH * NPIX) {
        int n = PP / NPIX; int p = PP % NPIX;
        v = hid[(size_t)(n * 512 + c0 + c) * NPIX + p];
      }
      xt[c * 256 + lp] = v;
    }
    for (int i = tid; i < 32 * 54; i += 256) {
      int c = i / 54; int o = i % 54;
      wt[c * 56 + o] = (o < 18) ? sw[o * 512 + c0 + c] : lww[(o - 18) * 512 + c0 + c];
    }
    __syncthreads();
#pragma unroll 4
    for (int c = 0; c < 32; c++) {
      float xv = xt[c * 256 + tid];
      const float* wp = &wt[c * 56];
#pragma unroll
      for (int o = 0; o < 54; o++) acc[o] = fmaf(xv, wp[o], acc[o]);
    }
    __syncthreads();
  }

  if (P < N_BATCH * NPIX) {
    int n = P / NPIX; int p = P % NPIX;
    float raw[18];
#pragma unroll
    for (int o = 0; o < 18; o++) raw[o] = acc[o] + sb[o];
    size_t sbase = OFF_SCORES + ((size_t)n * KA + (size_t)p * 9) * 2;
#pragma unroll
    for (int o = 0; o < 18; o++) out[sbase + o] = raw[o];
    size_t lbase = OFF_LOCS + ((size_t)n * KA + (size_t)p * 9) * 4;
#pragma unroll
    for (int o = 0; o < 36; o++) out[lbase + o] = acc[18 + o] + lb[o];
#pragma unroll
    for (int a = 0; a < 9; a++) {
      float r0 = raw[2 * a], r1 = raw[2 * a + 1];
      float m = fmaxf(r0, r1);
      float e0 = expf(r0 - m), e1 = expf(r1 - m);
      fg[(size_t)n * KA + p * 9 + a] = e1 / (e0 + e1);
    }
  }
}

// ---------------- roi prep: loc2bbox + clip + size filter + sortable key ----------------
__global__ void k_prep(const float* __restrict__ out, const float* __restrict__ fg,
    const int* __restrict__ ihp, const int* __restrict__ iwp,
    float4* __restrict__ roi, u64* __restrict__ items) {
  int idx = blockIdx.x * 256 + threadIdx.x;
  if (idx >= N_BATCH * KA) return;
  int b = idx / KA; int k = idx % KA;
  float4 A = ((const float4*)out)[OFF_ANCH / 4 + k];
  float4 L = ((const float4*)out)[OFF_LOCS / 4 + (size_t)b * KA + k];
  float imh = (float)ihp[0], imw = (float)iwp[0];
  float h = A.z - A.x, w = A.w - A.y;
  float yc = A.x + 0.5f * h, xc = A.y + 0.5f * w;
  float cy = L.x * h + yc, cx = L.y * w + xc;
  float nh = expf(L.z) * h, nw = expf(L.w) * w;
  float y1 = cy - 0.5f * nh, x1 = cx - 0.5f * nw;
  float y2 = cy + 0.5f * nh, x2 = cx + 0.5f * nw;
  y1 = fminf(fmaxf(y1, 0.f), imh); y2 = fminf(fmaxf(y2, 0.f), imh);
  x1 = fminf(fmaxf(x1, 0.f), imw); x2 = fminf(fmaxf(x2, 0.f), imw);
  float hs = y2 - y1, wsz = x2 - x1;
  bool valid = (hs >= 16.f) && (wsz >= 16.f);
  float sc = valid ? fg[idx] : NEGV;
  u32 u = __float_as_uint(sc);
  u32 key = (u & 0x80000000u) ? ~u : (u | 0x80000000u);
  roi[(size_t)b * KA + k] = make_float4(y1, x1, y2, x2);
  items[(size_t)b * KA + k] = ((u64)key << 32) | (u32)(~(u32)k);
}

// ---------------- per-batch: radix-select top 6000 + bitonic sort ----------------
__global__ __launch_bounds__(1024) void k_select(const u64* __restrict__ items,
    const float4* __restrict__ roi, u64* __restrict__ sitems, float4* __restrict__ sbox) {
  const int b = blockIdx.x;
  const int tid = threadIdx.x;
  const int lane = tid & 63;
  const u64* it = items + (size_t)b * KA;
  __shared__ u64 arr[8192];
  __shared__ u32 hist[256];
  __shared__ u32 sh_need, sh_prefix, sh_cnt;
  if (tid == 0) { sh_need = N_PRE; sh_prefix = 0; sh_cnt = 0; }

  // 4-pass byte-wise radix select on high 32 bits (find kth=6000th largest key)
  for (int s = 3; s >= 0; s--) {
    for (int i = tid; i < 256; i += 1024) hist[i] = 0;
    __syncthreads();
    u32 prefix = sh_prefix;
    int t = 3 - s;
    for (int i = tid; i < KA; i += 1024) {
      u32 key = (u32)(it[i] >> 32);
      bool match = (t == 0) || ((key >> ((s + 1) * 8)) == prefix);
      if (match) atomicAdd(&hist[(key >> (s * 8)) & 255], 1u);
    }
    __syncthreads();
    if (tid == 0) {
      u32 need = sh_need; int chosen = 0;
      for (int bb = 255; bb >= 0; bb--) {
        if (need <= hist[bb]) { chosen = bb; break; }
        need -= hist[bb];
      }
      sh_need = need;
      sh_prefix = (prefix << 8) | (u32)chosen;
    }
    __syncthreads();
  }
  u32 kth = sh_prefix;

  // compact all items with key >= kth (wave-aggregated atomic)
  for (int i0 = 0; i0 < KA; i0 += 1024) {
    int i = i0 + tid;
    u64 v = (i < KA) ? it[i] : 0ull;
    bool sel = (i < KA) && ((u32)(v >> 32) >= kth);
    u64 bal = __ballot(sel);
    u32 cnt = (u32)__popcll(bal);
    u32 base = 0;
    if (lane == 0 && cnt) base = atomicAdd(&sh_cnt, cnt);
    base = (u32)__shfl((int)base, 0, 64);
    if (sel) {
      u32 pos = base + (u32)__popcll(bal & ((1ull << lane) - 1ull));
      if (pos < 8192) arr[pos] = v;
    }
  }
  __syncthreads();
  u32 T = sh_cnt; if (T > 8192) T = 8192;
  for (int i = (int)T + tid; i < 8192; i += 1024) arr[i] = 0ull;

  // bitonic sort, descending (key desc, then ~idx desc == idx asc)
  for (u32 k = 2; k <= 8192; k <<= 1) {
    for (u32 j = k >> 1; j > 0; j >>= 1) {
      __syncthreads();
      for (u32 i = tid; i < 8192; i += 1024) {
        u32 l = i ^ j;
        if (l > i) {
          u64 a = arr[i], c = arr[l];
          bool dir = ((i & k) == 0);
          if ((a < c) == dir) { arr[i] = c; arr[l] = a; }
        }
      }
    }
  }
  __syncthreads();
  for (int i = tid; i < N_PRE; i += 1024) {
    u64 v = arr[i];
    sitems[(size_t)b * N_PRE + i] = v;
    u32 kk = ~(u32)(v & 0xffffffffull);
    float4 bx = make_float4(0, 0, 0, 0);
    if (kk < KA) bx = roi[(size_t)b * KA + kk];
    sbox[(size_t)b * N_PRE + i] = bx;
  }
}

// ---------------- NMS suppression bitmask (upper-triangle 64x64 blocks) ----------------
__global__ __launch_bounds__(64) void k_mask(const float4* __restrict__ sbox,
    u64* __restrict__ mask, u64* __restrict__ diag) {
  const int cb = blockIdx.x, rb = blockIdx.y, b = blockIdx.z;
  if (cb < rb) return;
  const int tid = threadIdx.x;
  __shared__ float4 cbx[64];
  __shared__ float carea[64];
  int col0 = cb * 64;
  int c = col0 + tid;
  float4 v = (c < N_PRE) ? sbox[(size_t)b * N_PRE + c] : make_float4(0, 0, 0, 0);
  cbx[tid] = v;
  carea[tid] = (v.z - v.x) * (v.w - v.y);
  __syncthreads();
  int row = rb * 64 + tid;
  if (row >= N_PRE) return;
  float4 r = sbox[(size_t)b * N_PRE + row];
  float rarea = (r.z - r.x) * (r.w - r.y);
  u64 word = 0ull;
  for (int j = 0; j < 64; j++) {
    int cc = col0 + j;
    if (cc > row && cc < N_PRE) {
      float4 q = cbx[j];
      float ty = fmaxf(r.x, q.x), tx = fmaxf(r.y, q.y);
      float by = fminf(r.z, q.z), bx = fminf(r.w, q.w);
      float ihh = fmaxf(by - ty, 0.f), iww = fmaxf(bx - tx, 0.f);
      float inter = ihh * iww;
      float iou = inter / (rarea + carea[j] - inter + 1e-9f);
      if (iou > NMS_T) word |= (1ull << j);
    }
  }
  mask[((size_t)b * N_PRE + row) * NWORDS + cb] = word;
  if (cb == rb) diag[(size_t)b * N_PRE + row] = word;  // own-group suppression word
}

// ---------------- sequential NMS reduce (4-deep chained via diag) + outputs ----------------
__global__ __launch_bounds__(64) void k_nms_out(const u64* __restrict__ sitems,
    const float4* __restrict__ sbox, const u64* __restrict__ mask,
    const u64* __restrict__ diag, float* __restrict__ out) {
  const int b = blockIdx.x;
  const int lane = threadIdx.x;
  __shared__ u64 remv[NWORDS];
  __shared__ u64 pre[NWORDS];
  __shared__ u64 dia[N_PRE];
  __shared__ u32 keep[N_POST];
  for (int i = lane; i < NWORDS; i += 64) { remv[i] = 0ull; pre[i] = 0ull; }
  __syncthreads();
  u32 keyneg = ~__float_as_uint(NEGV);
  for (int i = lane; i < N_PRE; i += 64) {
    dia[i] = diag[(size_t)b * N_PRE + i];
    u32 key = (u32)(sitems[(size_t)b * N_PRE + i] >> 32);
    if (key == keyneg || key == 0u)
      atomicOr(&pre[i >> 6], 1ull << (i & 63));
  }
  if (lane == 0) pre[NWORDS - 1] |= ~((1ull << (N_PRE - 64 * (NWORDS - 1))) - 1ull);
  __syncthreads();

  int kc = 0;
  for (int g = 0; g < NWORDS && kc < N_POST; g++) {
    u64 done = 0ull;
    while (kc < N_POST) {
      u64 cur = remv[g] | pre[g] | done;
      if (cur == ~0ull) break;
      // chain up to 4 keeps using LDS-resident diag words (no global latency)
      int r0 = -1, r1 = -1, r2 = -1, r3 = -1; int m = 1;
      u64 c2 = cur;
      int bit = __ffsll((long long)(~c2)) - 1;
      r0 = g * 64 + bit; c2 |= (1ull << bit) | dia[r0]; done |= 1ull << bit;
      if (c2 != ~0ull && kc + 1 < N_POST) {
        bit = __ffsll((long long)(~c2)) - 1;
        r1 = g * 64 + bit; c2 |= (1ull << bit) | dia[r1]; done |= 1ull << bit; m = 2;
        if (c2 != ~0ull && kc + 2 < N_POST) {
          bit = __ffsll((long long)(~c2)) - 1;
          r2 = g * 64 + bit; c2 |= (1ull << bit) | dia[r2]; done |= 1ull << bit; m = 3;
          if (c2 != ~0ull && kc + 3 < N_POST) {
            bit = __ffsll((long long)(~c2)) - 1;
            r3 = g * 64 + bit; c2 |= (1ull << bit) | dia[r3]; done |= 1ull << bit; m = 4;
          }
        }
      }
      if (lane == 0) {
        keep[kc] = (u32)r0;
        if (m > 1) keep[kc + 1] = (u32)r1;
        if (m > 2) keep[kc + 2] = (u32)r2;
        if (m > 3) keep[kc + 3] = (u32)r3;
      }
      // OR the m mask rows into remv in parallel: lane j*16+l16 handles row j
      int j = lane >> 4, l16 = lane & 15;
      int rj = (j == 0) ? r0 : (j == 1) ? r1 : (j == 2) ? r2 : r3;
      if (j < m) {
        const u64* mrow = mask + ((size_t)b * N_PRE + rj) * NWORDS;
        for (int cb = g + l16; cb < NWORDS; cb += 16)
          atomicOr(&remv[cb], mrow[cb]);
      }
      kc += m;
      __syncthreads();
    }
  }
  __syncthreads();
  for (int r = lane; r < N_POST; r += 64) {
    float4 bx = make_float4(0, 0, 0, 0);
    if (r < kc) bx = sbox[(size_t)b * N_PRE + keep[r]];
    ((float4*)out)[OFF_ROIS / 4 + (size_t)b * N_POST + r] = bx;
    out[OFF_RIDX + (size_t)b * N_POST + r] = (float)b;
  }
}

// ---------------- launch ----------------
extern "C" void kernel_launch(void* const* d_in, const int* in_sizes, int n_in,
                              void* d_out, int out_size, void* d_ws, size_t ws_size,
                              hipStream_t stream) {
  const float* x   = (const float*)d_in[0];
  const float* c1w = (const float*)d_in[1];
  const float* c1b = (const float*)d_in[2];
  const float* sw  = (const float*)d_in[3];
  const float* sb  = (const float*)d_in[4];
  const float* lw  = (const float*)d_in[5];
  const float* lb  = (const float*)d_in[6];
  const int* ih    = (const int*)d_in[7];
  const int* iw    = (const int*)d_in[8];
  float* out = (float*)d_out;
  char* wsb = (char*)d_ws;

  float* hid   = (float*)(wsb + WS_HID);
  float* fg    = (float*)(wsb + WS_FG);
  float4* roi  = (float4*)(wsb + WS_ROI);
  u64* items   = (u64*)(wsb + WS_ITEMS);
  u64* sitems  = (u64*)(wsb + WS_SITEMS);
  float4* sbox = (float4*)(wsb + WS_SBOX);
  u64* maskp   = (u64*)(wsb + WS_MASK);
  u64* diagp   = (u64*)(wsb + WS_DIAG);
  float* wT    = (float*)(wsb + WS_WT);

  hipLaunchKernelGGL(k_anchor, dim3((KA + 255) / 256), dim3(256), 0, stream, out);
  hipLaunchKernelGGL(k_wt, dim3(64, 16), dim3(256), 0, stream, c1w, wT);
  hipLaunchKernelGGL(k_conv1, dim3(32, 17, 2), dim3(256), 0, stream, x, wT, c1b, hid);
  hipLaunchKernelGGL(k_head, dim3((N_BATCH * NPIX + 255) / 256), dim3(256), 0, stream,
                     hid, sw, sb, lw, lb, out, fg);
  hipLaunchKernelGGL(k_prep, dim3((N_BATCH * KA + 255) / 256), dim3(256), 0, stream,
                     out, fg, ih, iw, roi, items);
  hipLaunchKernelGGL(k_select, dim3(2), dim3(1024), 0, stream, items, roi, sitems, sbox);
  hipLaunchKernelGGL(k_mask, dim3(NWORDS, NWORDS, 2), dim3(64), 0, stream, sbox, maskp, diagp);
  hipLaunchKernelGGL(k_nms_out, dim3(2), dim3(64), 0, stream, sitems, sbox, maskp, diagp, out);
}

// Round 5
// 1407.957 us; speedup vs baseline: 2.8882x; 2.8882x over previous
//
#include <hip/hip_runtime.h>
#include <hip/hip_bf16.h>
#include <math.h>

// ---------------- problem constants ----------------
#define N_BATCH 2
#define HH 50
#define WW 84
#define NPIX (HH*WW)           // 4200
#define KA (NPIX*9)            // 37800
#define N_PRE 6000
#define N_POST 300
#define NMS_T 0.7f
#define NEGV (-1e9f)
#define NWORDS 94              // ceil(6000/64)

// d_out offsets (floats)
#define OFF_LOCS   0
#define OFF_SCORES (N_BATCH*KA*4)                  // 302400
#define OFF_ROIS   (OFF_SCORES + N_BATCH*KA*2)     // 453600
#define OFF_RIDX   (OFF_ROIS + N_BATCH*N_POST*4)   // 456000
#define OFF_ANCH   (OFF_RIDX + N_BATCH*N_POST)     // 456600

// ws offsets (bytes), all 16B aligned
#define WS_HID    0ull
#define WS_FG     17203200ull
#define WS_ROI    17505600ull
#define WS_ITEMS  18715200ull
#define WS_SITEMS 19320000ull
#define WS_SBOX   19416000ull
#define WS_MASK   19608000ull
#define WS_DIAG   28632000ull   // 2*6000*8 = 96000 B
// wT2 (9.44 MB) lives at WS_ITEMS..+9.4MB during k_wt/k_conv1 only; those
// bytes (items/sitems/sbox/mask-start) are all written later in the stream.
#define WS_WT     WS_ITEMS

typedef unsigned long long u64;
typedef unsigned u32;

// ---------------- anchors ----------------
__global__ void k_anchor(float* __restrict__ out) {
  int k = blockIdx.x * 256 + threadIdx.x;
  if (k >= KA) return;
  int a = k % 9; int pj = k / 9; int j = pj % WW; int i = pj / WW;
  int ri = a / 3, si = a % 3;
  double ratio = (ri == 0) ? 0.5 : ((ri == 1) ? 1.0 : 2.0);
  double scale = (si == 0) ? 8.0 : ((si == 1) ? 16.0 : 32.0);
  double h = 16.0 * scale * sqrt(ratio);
  double w = 16.0 * scale * sqrt(1.0 / ratio);
  float y1 = (float)(8.0 - h * 0.5), x1 = (float)(8.0 - w * 0.5);
  float y2 = (float)(8.0 + h * 0.5), x2 = (float)(8.0 + w * 0.5);
  float sy = (float)(i * 16), sx = (float)(j * 16);
  ((float4*)out)[OFF_ANCH / 4 + k] = make_float4(sy + y1, sx + x1, sy + y2, sx + x2);
}

// ---------------- weight shuffle ----------------
// wT2[(t*4+ocb)*4608 + ((kx*3+ky)*4+ic)*128 + ocl] = w[(ocb*128+ocl)*4608 + t*36 + ic*9+ky*3+kx]
// grid (128 t, 4 ocb), 256 thr; LDS tile transpose for coalescing.
__global__ __launch_bounds__(256) void k_wt(const float* __restrict__ w,
    float* __restrict__ wT2) {
  const int t = blockIdx.x, ocb = blockIdx.y;
  const int tid = threadIdx.x;
  __shared__ float ls[128][37];
  for (int j = 0; j < 18; j++) {
    int idx = tid + j * 256;           // 0..4607
    int oc = idx / 36, r = idx % 36;
    ls[oc][r] = w[(size_t)(ocb * 128 + oc) * 4608 + t * 36 + r];
  }
  __syncthreads();
  float* outp = wT2 + (size_t)(t * 4 + ocb) * 4608;
  for (int j = 0; j < 18; j++) {
    int idx = tid + j * 256;
    int s36 = idx / 128, oc = idx % 128;
    int q = s36 >> 2, ic = s36 & 3;
    int kx = q / 3, ky = q % 3;
    outp[idx] = ls[oc][ic * 9 + ky * 3 + kx];
  }
}

// ---------------- conv1 3x3 512->512 + relu ----------------
// 256 thr = 128 oc x 2 rows x 84 px; thread = 4 oc x 21 px (84 acc).
// grid (4,25,2) = 200 blocks. IC_T=4. Per (ic,ky): 6+3 ds_read_b128 = 108 cyc
// vs 504 FMA cyc -> FMA-issue-bound. Reg-staged prefetch hides global latency.
#define IC_T 4
__global__ __launch_bounds__(256) void k_conv1(const float* __restrict__ x,
    const float* __restrict__ wT2, const float* __restrict__ bias,
    float* __restrict__ hid) {
  const int ocb  = blockIdx.x;   // 0..3
  const int rowb = blockIdx.y;   // 0..24
  const int n    = blockIdx.z;   // 0..1
  const int tid  = threadIdx.x;
  const int g    = tid & 3;          // px group (21 px)
  const int tr   = (tid >> 2) & 1;   // row within block
  const int ocl  = tid >> 3;         // 0..31 (4 oc each)
  const int row0 = rowb * 2;

  __shared__ __align__(16) float lx[IC_T * 4 * 96];   // [ic][rr(4)][4g*24] 6KB
  __shared__ __align__(16) float lw[IC_T * 9 * 128];  // [(kx*3+ky)*4+ic][128] 18.4KB

  const float* xg = x + (size_t)n * 512 * NPIX;

  // x staging map: 1536 floats, 6/thread
  int goff[6];
#pragma unroll
  for (int j = 0; j < 6; j++) {
    int idx = tid + j * 256;
    int ic = idx / 384; int rem = idx % 384;
    int rr = rem / 96;  int rem2 = rem % 96;
    int g2 = rem2 / 24; int q = rem2 % 24;
    int grow = row0 - 1 + rr;
    int gcol = g2 * 21 - 1 + q;
    bool v = ((unsigned)grow < 50u) && ((unsigned)gcol < 84u);
    goff[j] = v ? (ic * NPIX + grow * 84 + gcol) : -1;
  }

  float acc[4][21];
#pragma unroll
  for (int i = 0; i < 4; i++)
#pragma unroll
    for (int p = 0; p < 21; p++) acc[i][p] = 0.f;

  float xs[6], wsv[18];
  const float* wt0 = wT2 + (size_t)ocb * 4608;  // + t*4*4608 per tile
  // prologue: stage tile 0
#pragma unroll
  for (int j = 0; j < 6; j++) xs[j] = (goff[j] >= 0) ? xg[goff[j]] : 0.f;
#pragma unroll
  for (int j = 0; j < 18; j++) wsv[j] = wt0[tid + j * 256];

  for (int t = 0; t < 512 / IC_T; t++) {
    // commit staged regs to LDS
#pragma unroll
    for (int j = 0; j < 6; j++) lx[tid + j * 256] = xs[j];
#pragma unroll
    for (int j = 0; j < 18; j++) lw[tid + j * 256] = wsv[j];
    __syncthreads();

    // prefetch next tile (hidden under compute)
    if (t < 512 / IC_T - 1) {
      int xadv = (t + 1) * IC_T * NPIX;
      const float* wtn = wt0 + (size_t)(t + 1) * 4 * 4608;
#pragma unroll
      for (int j = 0; j < 6; j++) xs[j] = (goff[j] >= 0) ? xg[goff[j] + xadv] : 0.f;
#pragma unroll
      for (int j = 0; j < 18; j++) wsv[j] = wtn[tid + j * 256];
    }

    // compute current tile
#pragma unroll
    for (int ic = 0; ic < IC_T; ic++) {
#pragma unroll
      for (int ky = 0; ky < 3; ky++) {
        float xv[24];
        const float* lp = &lx[ic * 384 + (tr + ky) * 96 + g * 24];
#pragma unroll
        for (int v4 = 0; v4 < 6; v4++) {
          float4 f = *(const float4*)&lp[v4 * 4];
          xv[v4 * 4 + 0] = f.x; xv[v4 * 4 + 1] = f.y;
          xv[v4 * 4 + 2] = f.z; xv[v4 * 4 + 3] = f.w;
        }
#pragma unroll
        for (int kx = 0; kx < 3; kx++) {
          float4 wv = *(const float4*)&lw[((kx * 3 + ky) * IC_T + ic) * 128 + ocl * 4];
          float wa[4] = {wv.x, wv.y, wv.z, wv.w};
#pragma unroll
          for (int i = 0; i < 4; i++)
#pragma unroll
            for (int p = 0; p < 21; p++)
              acc[i][p] = fmaf(wa[i], xv[p + kx], acc[i][p]);
        }
      }
    }
    __syncthreads();
  }

  {
    int oc = ocb * 128 + ocl * 4;
    int prow = row0 + tr;
#pragma unroll
    for (int i = 0; i < 4; i++) {
      float bv = bias[oc + i];
      float* op = &hid[(size_t)(n * 512 + oc + i) * NPIX + prow * 84 + g * 21];
#pragma unroll
      for (int p = 0; p < 21; p++) { float v = acc[i][p] + bv; op[p] = v > 0.f ? v : 0.f; }
    }
  }
}

// ---------------- 1x1 heads (18 score + 36 loc) + fg softmax ----------------
__global__ __launch_bounds__(256) void k_head(const float* __restrict__ hid,
    const float* __restrict__ sw, const float* __restrict__ sb,
    const float* __restrict__ lww, const float* __restrict__ lb,
    float* __restrict__ out, float* __restrict__ fg) {
  const int tid = threadIdx.x;
  const int P0 = blockIdx.x * 256;
  const int P = P0 + tid;
  __shared__ float xt[32 * 256];
  __shared__ float wt[32 * 56];
  float acc[54];
#pragma unroll
  for (int o = 0; o < 54; o++) acc[o] = 0.f;

  for (int c0 = 0; c0 < 512; c0 += 32) {
    for (int i = tid; i < 32 * 256; i += 256) {
      int c = i >> 8; int lp = i & 255;
      int PP = P0 + lp;
      float v = 0.f;
      if (PP < N_BATCH * NPIX) {
        int n = PP / NPIX; int p = PP % NPIX;
        v = hid[(size_t)(n * 512 + c0 + c) * NPIX + p];
      }
      xt[c * 256 + lp] = v;
    }
    for (int i = tid; i < 32 * 54; i += 256) {
      int c = i / 54; int o = i % 54;
      wt[c * 56 + o] = (o < 18) ? sw[o * 512 + c0 + c] : lww[(o - 18) * 512 + c0 + c];
    }
    __syncthreads();
#pragma unroll 4
    for (int c = 0; c < 32; c++) {
      float xv = xt[c * 256 + tid];
      const float* wp = &wt[c * 56];
#pragma unroll
      for (int o = 0; o < 54; o++) acc[o] = fmaf(xv, wp[o], acc[o]);
    }
    __syncthreads();
  }

  if (P < N_BATCH * NPIX) {
    int n = P / NPIX; int p = P % NPIX;
    float raw[18];
#pragma unroll
    for (int o = 0; o < 18; o++) raw[o] = acc[o] + sb[o];
    size_t sbase = OFF_SCORES + ((size_t)n * KA + (size_t)p * 9) * 2;
#pragma unroll
    for (int o = 0; o < 18; o++) out[sbase + o] = raw[o];
    size_t lbase = OFF_LOCS + ((size_t)n * KA + (size_t)p * 9) * 4;
#pragma unroll
    for (int o = 0; o < 36; o++) out[lbase + o] = acc[18 + o] + lb[o];
#pragma unroll
    for (int a = 0; a < 9; a++) {
      float r0 = raw[2 * a], r1 = raw[2 * a + 1];
      float m = fmaxf(r0, r1);
      float e0 = expf(r0 - m), e1 = expf(r1 - m);
      fg[(size_t)n * KA + p * 9 + a] = e1 / (e0 + e1);
    }
  }
}

// ---------------- roi prep: loc2bbox + clip + size filter + sortable key ----------------
__global__ void k_prep(const float* __restrict__ out, const float* __restrict__ fg,
    const int* __restrict__ ihp, const int* __restrict__ iwp,
    float4* __restrict__ roi, u64* __restrict__ items) {
  int idx = blockIdx.x * 256 + threadIdx.x;
  if (idx >= N_BATCH * KA) return;
  int b = idx / KA; int k = idx % KA;
  float4 A = ((const float4*)out)[OFF_ANCH / 4 + k];
  float4 L = ((const float4*)out)[OFF_LOCS / 4 + (size_t)b * KA + k];
  float imh = (float)ihp[0], imw = (float)iwp[0];
  float h = A.z - A.x, w = A.w - A.y;
  float yc = A.x + 0.5f * h, xc = A.y + 0.5f * w;
  float cy = L.x * h + yc, cx = L.y * w + xc;
  float nh = expf(L.z) * h, nw = expf(L.w) * w;
  float y1 = cy - 0.5f * nh, x1 = cx - 0.5f * nw;
  float y2 = cy + 0.5f * nh, x2 = cx + 0.5f * nw;
  y1 = fminf(fmaxf(y1, 0.f), imh); y2 = fminf(fmaxf(y2, 0.f), imh);
  x1 = fminf(fmaxf(x1, 0.f), imw); x2 = fminf(fmaxf(x2, 0.f), imw);
  float hs = y2 - y1, wsz = x2 - x1;
  bool valid = (hs >= 16.f) && (wsz >= 16.f);
  float sc = valid ? fg[idx] : NEGV;
  u32 u = __float_as_uint(sc);
  u32 key = (u & 0x80000000u) ? ~u : (u | 0x80000000u);
  roi[(size_t)b * KA + k] = make_float4(y1, x1, y2, x2);
  items[(size_t)b * KA + k] = ((u64)key << 32) | (u32)(~(u32)k);
}

// ---------------- per-batch: radix-select top 6000 + bitonic sort ----------------
// histogram via per-2-wave sub-hists in the (then-unused) arr region: no hot-
// bucket cross-block contention (pass 1 concentrates ~6 exponent buckets).
__global__ __launch_bounds__(1024) void k_select(const u64* __restrict__ items,
    const float4* __restrict__ roi, u64* __restrict__ sitems, float4* __restrict__ sbox) {
  const int b = blockIdx.x;
  const int tid = threadIdx.x;
  const int lane = tid & 63;
  const int slice = tid >> 7;        // 0..7 (2 waves per sub-hist)
  const u64* it = items + (size_t)b * KA;
  __shared__ u64 arr[8192];
  __shared__ u32 hist[256];
  __shared__ u32 sh_need, sh_prefix, sh_cnt;
  u32* h8 = (u32*)arr;               // 8*256 u32 sub-hists (dead before sort)
  if (tid == 0) { sh_need = N_PRE; sh_prefix = 0; sh_cnt = 0; }

  for (int s = 3; s >= 0; s--) {
    for (int i = tid; i < 2048; i += 1024) h8[i] = 0;
    __syncthreads();
    u32 prefix = sh_prefix;
    int t = 3 - s;
    for (int i = tid; i < KA; i += 1024) {
      u32 key = (u32)(it[i] >> 32);
      bool match = (t == 0) || ((key >> ((s + 1) * 8)) == prefix);
      if (match) atomicAdd(&h8[slice * 256 + ((key >> (s * 8)) & 255)], 1u);
    }
    __syncthreads();
    if (tid < 256) {
      u32 sum = 0;
#pragma unroll
      for (int k = 0; k < 8; k++) sum += h8[k * 256 + tid];
      hist[tid] = sum;
    }
    __syncthreads();
    if (tid == 0) {
      u32 need = sh_need; int chosen = 0;
      for (int bb = 255; bb >= 0; bb--) {
        if (need <= hist[bb]) { chosen = bb; break; }
        need -= hist[bb];
      }
      sh_need = need;
      sh_prefix = (prefix << 8) | (u32)chosen;
    }
    __syncthreads();
  }
  u32 kth = sh_prefix;

  // compact all items with key >= kth (wave-aggregated atomic)
  for (int i0 = 0; i0 < KA; i0 += 1024) {
    int i = i0 + tid;
    u64 v = (i < KA) ? it[i] : 0ull;
    bool sel = (i < KA) && ((u32)(v >> 32) >= kth);
    u64 bal = __ballot(sel);
    u32 cnt = (u32)__popcll(bal);
    u32 base = 0;
    if (lane == 0 && cnt) base = atomicAdd(&sh_cnt, cnt);
    base = (u32)__shfl((int)base, 0, 64);
    if (sel) {
      u32 pos = base + (u32)__popcll(bal & ((1ull << lane) - 1ull));
      if (pos < 8192) arr[pos] = v;
    }
  }
  __syncthreads();
  u32 T = sh_cnt; if (T > 8192) T = 8192;
  for (int i = (int)T + tid; i < 8192; i += 1024) arr[i] = 0ull;

  // bitonic sort, descending (key desc, then ~idx desc == idx asc)
  for (u32 k = 2; k <= 8192; k <<= 1) {
    for (u32 j = k >> 1; j > 0; j >>= 1) {
      __syncthreads();
      for (u32 i = tid; i < 8192; i += 1024) {
        u32 l = i ^ j;
        if (l > i) {
          u64 a = arr[i], c = arr[l];
          bool dir = ((i & k) == 0);
          if ((a < c) == dir) { arr[i] = c; arr[l] = a; }
        }
      }
    }
  }
  __syncthreads();
  for (int i = tid; i < N_PRE; i += 1024) {
    u64 v = arr[i];
    sitems[(size_t)b * N_PRE + i] = v;
    u32 kk = ~(u32)(v & 0xffffffffull);
    float4 bx = make_float4(0, 0, 0, 0);
    if (kk < KA) bx = roi[(size_t)b * KA + kk];
    sbox[(size_t)b * N_PRE + i] = bx;
  }
}

// ---------------- NMS suppression bitmask (upper-triangle 64x64 blocks) ----------------
__global__ __launch_bounds__(64) void k_mask(const float4* __restrict__ sbox,
    u64* __restrict__ mask, u64* __restrict__ diag) {
  const int cb = blockIdx.x, rb = blockIdx.y, b = blockIdx.z;
  if (cb < rb) return;
  const int tid = threadIdx.x;
  __shared__ float4 cbx[64];
  __shared__ float carea[64];
  int col0 = cb * 64;
  int c = col0 + tid;
  float4 v = (c < N_PRE) ? sbox[(size_t)b * N_PRE + c] : make_float4(0, 0, 0, 0);
  cbx[tid] = v;
  carea[tid] = (v.z - v.x) * (v.w - v.y);
  __syncthreads();
  int row = rb * 64 + tid;
  if (row >= N_PRE) return;
  float4 r = sbox[(size_t)b * N_PRE + row];
  float rarea = (r.z - r.x) * (r.w - r.y);
  u64 word = 0ull;
  for (int j = 0; j < 64; j++) {
    int cc = col0 + j;
    if (cc > row && cc < N_PRE) {
      float4 q = cbx[j];
      float ty = fmaxf(r.x, q.x), tx = fmaxf(r.y, q.y);
      float by = fminf(r.z, q.z), bx = fminf(r.w, q.w);
      float ihh = fmaxf(by - ty, 0.f), iww = fmaxf(bx - tx, 0.f);
      float inter = ihh * iww;
      float iou = inter / (rarea + carea[j] - inter + 1e-9f);
      if (iou > NMS_T) word |= (1ull << j);
    }
  }
  mask[((size_t)b * N_PRE + row) * NWORDS + cb] = word;
  if (cb == rb) diag[(size_t)b * N_PRE + row] = word;  // own-group suppression word
}

// ---------------- sequential NMS reduce (4-deep chained via diag) + outputs ----------------
__global__ __launch_bounds__(64) void k_nms_out(const u64* __restrict__ sitems,
    const float4* __restrict__ sbox, const u64* __restrict__ mask,
    const u64* __restrict__ diag, float* __restrict__ out) {
  const int b = blockIdx.x;
  const int lane = threadIdx.x;
  __shared__ u64 remv[NWORDS];
  __shared__ u64 pre[NWORDS];
  __shared__ u64 dia[N_PRE];
  __shared__ u32 keep[N_POST];
  for (int i = lane; i < NWORDS; i += 64) { remv[i] = 0ull; pre[i] = 0ull; }
  __syncthreads();
  u32 keyneg = ~__float_as_uint(NEGV);
  for (int i = lane; i < N_PRE; i += 64) {
    dia[i] = diag[(size_t)b * N_PRE + i];
    u32 key = (u32)(sitems[(size_t)b * N_PRE + i] >> 32);
    if (key == keyneg || key == 0u)
      atomicOr(&pre[i >> 6], 1ull << (i & 63));
  }
  if (lane == 0) pre[NWORDS - 1] |= ~((1ull << (N_PRE - 64 * (NWORDS - 1))) - 1ull);
  __syncthreads();

  int kc = 0;
  for (int g = 0; g < NWORDS && kc < N_POST; g++) {
    u64 done = 0ull;
    while (kc < N_POST) {
      u64 cur = remv[g] | pre[g] | done;
      if (cur == ~0ull) break;
      int r0 = -1, r1 = -1, r2 = -1, r3 = -1; int m = 1;
      u64 c2 = cur;
      int bit = __ffsll((long long)(~c2)) - 1;
      r0 = g * 64 + bit; c2 |= (1ull << bit) | dia[r0]; done |= 1ull << bit;
      if (c2 != ~0ull && kc + 1 < N_POST) {
        bit = __ffsll((long long)(~c2)) - 1;
        r1 = g * 64 + bit; c2 |= (1ull << bit) | dia[r1]; done |= 1ull << bit; m = 2;
        if (c2 != ~0ull && kc + 2 < N_POST) {
          bit = __ffsll((long long)(~c2)) - 1;
          r2 = g * 64 + bit; c2 |= (1ull << bit) | dia[r2]; done |= 1ull << bit; m = 3;
          if (c2 != ~0ull && kc + 3 < N_POST) {
            bit = __ffsll((long long)(~c2)) - 1;
            r3 = g * 64 + bit; c2 |= (1ull << bit) | dia[r3]; done |= 1ull << bit; m = 4;
          }
        }
      }
      if (lane == 0) {
        keep[kc] = (u32)r0;
        if (m > 1) keep[kc + 1] = (u32)r1;
        if (m > 2) keep[kc + 2] = (u32)r2;
        if (m > 3) keep[kc + 3] = (u32)r3;
      }
      int j = lane >> 4, l16 = lane & 15;
      int rj = (j == 0) ? r0 : (j == 1) ? r1 : (j == 2) ? r2 : r3;
      if (j < m) {
        const u64* mrow = mask + ((size_t)b * N_PRE + rj) * NWORDS;
        for (int cb = g + l16; cb < NWORDS; cb += 16)
          atomicOr(&remv[cb], mrow[cb]);
      }
      kc += m;
      __syncthreads();
    }
  }
  __syncthreads();
  for (int r = lane; r < N_POST; r += 64) {
    float4 bx = make_float4(0, 0, 0, 0);
    if (r < kc) bx = sbox[(size_t)b * N_PRE + keep[r]];
    ((float4*)out)[OFF_ROIS / 4 + (size_t)b * N_POST + r] = bx;
    out[OFF_RIDX + (size_t)b * N_POST + r] = (float)b;
  }
}

// ---------------- launch ----------------
extern "C" void kernel_launch(void* const* d_in, const int* in_sizes, int n_in,
                              void* d_out, int out_size, void* d_ws, size_t ws_size,
                              hipStream_t stream) {
  const float* x   = (const float*)d_in[0];
  const float* c1w = (const float*)d_in[1];
  const float* c1b = (const float*)d_in[2];
  const float* sw  = (const float*)d_in[3];
  const float* sb  = (const float*)d_in[4];
  const float* lw  = (const float*)d_in[5];
  const float* lb  = (const float*)d_in[6];
  const int* ih    = (const int*)d_in[7];
  const int* iw    = (const int*)d_in[8];
  float* out = (float*)d_out;
  char* wsb = (char*)d_ws;

  float* hid   = (float*)(wsb + WS_HID);
  float* fg    = (float*)(wsb + WS_FG);
  float4* roi  = (float4*)(wsb + WS_ROI);
  u64* items   = (u64*)(wsb + WS_ITEMS);
  u64* sitems  = (u64*)(wsb + WS_SITEMS);
  float4* sbox = (float4*)(wsb + WS_SBOX);
  u64* maskp   = (u64*)(wsb + WS_MASK);
  u64* diagp   = (u64*)(wsb + WS_DIAG);
  float* wT2   = (float*)(wsb + WS_WT);

  hipLaunchKernelGGL(k_anchor, dim3((KA + 255) / 256), dim3(256), 0, stream, out);
  hipLaunchKernelGGL(k_wt, dim3(128, 4), dim3(256), 0, stream, c1w, wT2);
  hipLaunchKernelGGL(k_conv1, dim3(4, 25, 2), dim3(256), 0, stream, x, wT2, c1b, hid);
  hipLaunchKernelGGL(k_head, dim3((N_BATCH * NPIX + 255) / 256), dim3(256), 0, stream,
                     hid, sw, sb, lw, lb, out, fg);
  hipLaunchKernelGGL(k_prep, dim3((N_BATCH * KA + 255) / 256), dim3(256), 0, stream,
                     out, fg, ih, iw, roi, items);
  hipLaunchKernelGGL(k_select, dim3(2), dim3(1024), 0, stream, items, roi, sitems, sbox);
  hipLaunchKernelGGL(k_mask, dim3(NWORDS, NWORDS, 2), dim3(64), 0, stream, sbox, maskp, diagp);
  hipLaunchKernelGGL(k_nms_out, dim3(2), dim3(64), 0, stream, sitems, sbox, maskp, diagp, out);
}

// Round 6
// 1375.352 us; speedup vs baseline: 2.9567x; 1.0237x over previous
//
#include <hip/hip_runtime.h>
#include <hip/hip_bf16.h>
#include <math.h>

// ---------------- problem constants ----------------
#define N_BATCH 2
#define HH 50
#define WW 84
#define NPIX (HH*WW)           // 4200
#define KA (NPIX*9)            // 37800
#define N_PRE 6000
#define N_POST 300
#define NMS_T 0.7f
#define NEGV (-1e9f)
#define NWORDS 94              // ceil(6000/64)

// d_out offsets (floats)
#define OFF_LOCS   0
#define OFF_SCORES (N_BATCH*KA*4)                  // 302400
#define OFF_ROIS   (OFF_SCORES + N_BATCH*KA*2)     // 453600
#define OFF_RIDX   (OFF_ROIS + N_BATCH*N_POST*4)   // 456000
#define OFF_ANCH   (OFF_RIDX + N_BATCH*N_POST)     // 456600

// ws offsets (bytes), all 16B aligned
#define WS_HID    0ull
#define WS_FG     17203200ull
#define WS_ROI    17505600ull
#define WS_ITEMS  18715200ull
#define WS_SITEMS 19320000ull
#define WS_SBOX   19416000ull
#define WS_MASK   19608000ull
#define WS_DIAG   28632000ull   // 2*6000*8 = 96000 B
// wT2 (9.44 MB) lives at WS_ITEMS..+9.4MB during k_init/k_conv1 only; those
// bytes (items/sitems/sbox/mask-start) are all written later in the stream.
#define WS_WT     WS_ITEMS

typedef unsigned long long u64;
typedef unsigned u32;

// ---------------- init: anchors (blocks 0..147) + weight shuffle (148..659) ----
// wT2[(t*4+ocb)*4608 + ((kx*3+ky)*4+ic)*128 + ocl] =
//   w[(ocb*128+ocl)*4608 + t*36 + ic*9+ky*3+kx]
__global__ __launch_bounds__(256) void k_init(const float* __restrict__ w,
    float* __restrict__ wT2, float* __restrict__ out) {
  __shared__ float ls[128][37];
  const int b = blockIdx.x;
  const int tid = threadIdx.x;
  if (b < 148) {
    int k = b * 256 + tid;
    if (k >= KA) return;
    int a = k % 9; int pj = k / 9; int j = pj % WW; int i = pj / WW;
    int ri = a / 3, si = a % 3;
    double ratio = (ri == 0) ? 0.5 : ((ri == 1) ? 1.0 : 2.0);
    double scale = (si == 0) ? 8.0 : ((si == 1) ? 16.0 : 32.0);
    double h = 16.0 * scale * sqrt(ratio);
    double ww2 = 16.0 * scale * sqrt(1.0 / ratio);
    float y1 = (float)(8.0 - h * 0.5), x1 = (float)(8.0 - ww2 * 0.5);
    float y2 = (float)(8.0 + h * 0.5), x2 = (float)(8.0 + ww2 * 0.5);
    float sy = (float)(i * 16), sx = (float)(j * 16);
    ((float4*)out)[OFF_ANCH / 4 + k] = make_float4(sy + y1, sx + x1, sy + y2, sx + x2);
  } else {
    const int bb = b - 148;
    const int t = bb >> 2, ocb = bb & 3;
    for (int j = 0; j < 18; j++) {
      int idx = tid + j * 256;           // 0..4607
      int oc = idx / 36, r = idx % 36;
      ls[oc][r] = w[(size_t)(ocb * 128 + oc) * 4608 + t * 36 + r];
    }
    __syncthreads();
    float* outp = wT2 + (size_t)(t * 4 + ocb) * 4608;
    for (int j = 0; j < 18; j++) {
      int idx = tid + j * 256;
      int s36 = idx / 128, oc = idx % 128;
      int q = s36 >> 2, ic = s36 & 3;
      int kx = q / 3, ky = q % 3;
      outp[idx] = ls[oc][ic * 9 + ky * 3 + kx];
    }
  }
}

// ---------------- conv1 3x3 512->512 + relu ----------------
// 256 thr = 128 oc x 2 rows x 84 px; thread = 4 oc x 21 px (84 acc).
// grid (4,25,2) = 200 blocks (1 wave/SIMD, grid-limited). launch_bounds(256,1)
// frees VGPRs; explicit 2-deep (ic,ky)-unit pipeline: unit u+1's 9 ds_read_b128
// issue before unit u's 252 FMAs -> LDS latency hidden despite 1 wave/SIMD.
#define IC_T 4
__global__ __launch_bounds__(256, 1) void k_conv1(const float* __restrict__ x,
    const float* __restrict__ wT2, const float* __restrict__ bias,
    float* __restrict__ hid) {
  const int ocb  = blockIdx.x;   // 0..3
  const int rowb = blockIdx.y;   // 0..24
  const int n    = blockIdx.z;   // 0..1
  const int tid  = threadIdx.x;
  const int g    = tid & 3;          // px group (21 px)
  const int tr   = (tid >> 2) & 1;   // row within block
  const int ocl  = tid >> 3;         // 0..31 (4 oc each)
  const int row0 = rowb * 2;

  __shared__ __align__(16) float lx[IC_T * 4 * 96];   // 6KB
  __shared__ __align__(16) float lw[IC_T * 9 * 128];  // 18.4KB

  const float* xg = x + (size_t)n * 512 * NPIX;

  // x staging map: 1536 floats, 6/thread
  int goff[6];
#pragma unroll
  for (int j = 0; j < 6; j++) {
    int idx = tid + j * 256;
    int ic = idx / 384; int rem = idx % 384;
    int rr = rem / 96;  int rem2 = rem % 96;
    int g2 = rem2 / 24; int q = rem2 % 24;
    int grow = row0 - 1 + rr;
    int gcol = g2 * 21 - 1 + q;
    bool v = ((unsigned)grow < 50u) && ((unsigned)gcol < 84u);
    goff[j] = v ? (ic * NPIX + grow * 84 + gcol) : -1;
  }

  float acc[4][21];
#pragma unroll
  for (int i = 0; i < 4; i++)
#pragma unroll
    for (int p = 0; p < 21; p++) acc[i][p] = 0.f;

  float xs[6], wsv[18];
  const float* wt0 = wT2 + (size_t)ocb * 4608;  // + t*4*4608 per tile
  // prologue: stage tile 0
#pragma unroll
  for (int j = 0; j < 6; j++) xs[j] = (goff[j] >= 0) ? xg[goff[j]] : 0.f;
#pragma unroll
  for (int j = 0; j < 18; j++) wsv[j] = wt0[tid + j * 256];

  for (int t = 0; t < 512 / IC_T; t++) {
    // commit staged regs to LDS
#pragma unroll
    for (int j = 0; j < 6; j++) lx[tid + j * 256] = xs[j];
#pragma unroll
    for (int j = 0; j < 18; j++) lw[tid + j * 256] = wsv[j];
    __syncthreads();

    // issue next tile's global loads (hidden under compute)
    if (t < 512 / IC_T - 1) {
      int xadv = (t + 1) * IC_T * NPIX;
      const float* wtn = wt0 + (size_t)(t + 1) * 4 * 4608;
#pragma unroll
      for (int j = 0; j < 6; j++) xs[j] = (goff[j] >= 0) ? xg[goff[j] + xadv] : 0.f;
#pragma unroll
      for (int j = 0; j < 18; j++) wsv[j] = wtn[tid + j * 256];
    }

    // compute current tile: 12 (ic,ky) units, software-pipelined 2-deep
    float xv[2][24];
    float4 wv[2][3];
    {
      const float* lp = &lx[(tr + 0) * 96 + g * 24];  // ic=0, ky=0
#pragma unroll
      for (int v4 = 0; v4 < 6; v4++)
        *(float4*)&xv[0][v4 * 4] = *(const float4*)&lp[v4 * 4];
#pragma unroll
      for (int kx = 0; kx < 3; kx++)
        wv[0][kx] = *(const float4*)&lw[((kx * 3 + 0) * IC_T + 0) * 128 + ocl * 4];
    }
#pragma unroll
    for (int u = 0; u < 12; u++) {
      const int cur = u & 1, nxt = cur ^ 1;
      if (u < 11) {
        const int icn = (u + 1) / 3, kyn = (u + 1) % 3;
        const float* lp = &lx[icn * 384 + (tr + kyn) * 96 + g * 24];
#pragma unroll
        for (int v4 = 0; v4 < 6; v4++)
          *(float4*)&xv[nxt][v4 * 4] = *(const float4*)&lp[v4 * 4];
#pragma unroll
        for (int kx = 0; kx < 3; kx++)
          wv[nxt][kx] = *(const float4*)&lw[((kx * 3 + kyn) * IC_T + icn) * 128 + ocl * 4];
      }
#pragma unroll
      for (int kx = 0; kx < 3; kx++) {
        float wa[4] = {wv[cur][kx].x, wv[cur][kx].y, wv[cur][kx].z, wv[cur][kx].w};
#pragma unroll
        for (int i = 0; i < 4; i++)
#pragma unroll
          for (int p = 0; p < 21; p++)
            acc[i][p] = fmaf(wa[i], xv[cur][p + kx], acc[i][p]);
      }
    }
    __syncthreads();
  }

  {
    int oc = ocb * 128 + ocl * 4;
    int prow = row0 + tr;
#pragma unroll
    for (int i = 0; i < 4; i++) {
      float bv = bias[oc + i];
      float* op = &hid[(size_t)(n * 512 + oc + i) * NPIX + prow * 84 + g * 21];
#pragma unroll
      for (int p = 0; p < 21; p++) { float v = acc[i][p] + bv; op[p] = v > 0.f ? v : 0.f; }
    }
  }
}

// ---------------- 1x1 heads (18 score + 36 loc) + fg softmax ----------------
__global__ __launch_bounds__(256) void k_head(const float* __restrict__ hid,
    const float* __restrict__ sw, const float* __restrict__ sb,
    const float* __restrict__ lww, const float* __restrict__ lb,
    float* __restrict__ out, float* __restrict__ fg) {
  const int tid = threadIdx.x;
  const int P0 = blockIdx.x * 256;
  const int P = P0 + tid;
  __shared__ float xt[32 * 256];
  __shared__ float wt[32 * 56];
  float acc[54];
#pragma unroll
  for (int o = 0; o < 54; o++) acc[o] = 0.f;

  for (int c0 = 0; c0 < 512; c0 += 32) {
    for (int i = tid; i < 32 * 256; i += 256) {
      int c = i >> 8; int lp = i & 255;
      int PP = P0 + lp;
      float v = 0.f;
      if (PP < N_BATCH * NPIX) {
        int n = PP / NPIX; int p = PP % NPIX;
        v = hid[(size_t)(n * 512 + c0 + c) * NPIX + p];
      }
      xt[c * 256 + lp] = v;
    }
    for (int i = tid; i < 32 * 54; i += 256) {
      int c = i / 54; int o = i % 54;
      wt[c * 56 + o] = (o < 18) ? sw[o * 512 + c0 + c] : lww[(o - 18) * 512 + c0 + c];
    }
    __syncthreads();
#pragma unroll 4
    for (int c = 0; c < 32; c++) {
      float xv = xt[c * 256 + tid];
      const float* wp = &wt[c * 56];
#pragma unroll
      for (int o = 0; o < 54; o++) acc[o] = fmaf(xv, wp[o], acc[o]);
    }
    __syncthreads();
  }

  if (P < N_BATCH * NPIX) {
    int n = P / NPIX; int p = P % NPIX;
    float raw[18];
#pragma unroll
    for (int o = 0; o < 18; o++) raw[o] = acc[o] + sb[o];
    size_t sbase = OFF_SCORES + ((size_t)n * KA + (size_t)p * 9) * 2;
#pragma unroll
    for (int o = 0; o < 18; o++) out[sbase + o] = raw[o];
    size_t lbase = OFF_LOCS + ((size_t)n * KA + (size_t)p * 9) * 4;
#pragma unroll
    for (int o = 0; o < 36; o++) out[lbase + o] = acc[18 + o] + lb[o];
#pragma unroll
    for (int a = 0; a < 9; a++) {
      float r0 = raw[2 * a], r1 = raw[2 * a + 1];
      float m = fmaxf(r0, r1);
      float e0 = expf(r0 - m), e1 = expf(r1 - m);
      fg[(size_t)n * KA + p * 9 + a] = e1 / (e0 + e1);
    }
  }
}

// ---------------- roi prep: loc2bbox + clip + size filter + sortable key ----------------
__global__ void k_prep(const float* __restrict__ out, const float* __restrict__ fg,
    const int* __restrict__ ihp, const int* __restrict__ iwp,
    float4* __restrict__ roi, u64* __restrict__ items) {
  int idx = blockIdx.x * 256 + threadIdx.x;
  if (idx >= N_BATCH * KA) return;
  int b = idx / KA; int k = idx % KA;
  float4 A = ((const float4*)out)[OFF_ANCH / 4 + k];
  float4 L = ((const float4*)out)[OFF_LOCS / 4 + (size_t)b * KA + k];
  float imh = (float)ihp[0], imw = (float)iwp[0];
  float h = A.z - A.x, w = A.w - A.y;
  float yc = A.x + 0.5f * h, xc = A.y + 0.5f * w;
  float cy = L.x * h + yc, cx = L.y * w + xc;
  float nh = expf(L.z) * h, nw = expf(L.w) * w;
  float y1 = cy - 0.5f * nh, x1 = cx - 0.5f * nw;
  float y2 = cy + 0.5f * nh, x2 = cx + 0.5f * nw;
  y1 = fminf(fmaxf(y1, 0.f), imh); y2 = fminf(fmaxf(y2, 0.f), imh);
  x1 = fminf(fmaxf(x1, 0.f), imw); x2 = fminf(fmaxf(x2, 0.f), imw);
  float hs = y2 - y1, wsz = x2 - x1;
  bool valid = (hs >= 16.f) && (wsz >= 16.f);
  float sc = valid ? fg[idx] : NEGV;
  u32 u = __float_as_uint(sc);
  u32 key = (u & 0x80000000u) ? ~u : (u | 0x80000000u);
  roi[(size_t)b * KA + k] = make_float4(y1, x1, y2, x2);
  items[(size_t)b * KA + k] = ((u64)key << 32) | (u32)(~(u32)k);
}

// ---------------- per-batch: radix-select top 6000 + bitonic sort ----------------
__global__ __launch_bounds__(1024) void k_select(const u64* __restrict__ items,
    const float4* __restrict__ roi, u64* __restrict__ sitems, float4* __restrict__ sbox) {
  const int b = blockIdx.x;
  const int tid = threadIdx.x;
  const int lane = tid & 63;
  const int slice = tid >> 7;        // 0..7 (2 waves per sub-hist)
  const u64* it = items + (size_t)b * KA;
  __shared__ u64 arr[8192];
  __shared__ u32 hist[256];
  __shared__ u32 sh_need, sh_prefix, sh_cnt;
  u32* h8 = (u32*)arr;               // 8*256 u32 sub-hists (dead before sort)
  if (tid == 0) { sh_need = N_PRE; sh_prefix = 0; sh_cnt = 0; }

  for (int s = 3; s >= 0; s--) {
    for (int i = tid; i < 2048; i += 1024) h8[i] = 0;
    __syncthreads();
    u32 prefix = sh_prefix;
    int t = 3 - s;
    for (int i = tid; i < KA; i += 1024) {
      u32 key = (u32)(it[i] >> 32);
      bool match = (t == 0) || ((key >> ((s + 1) * 8)) == prefix);
      if (match) atomicAdd(&h8[slice * 256 + ((key >> (s * 8)) & 255)], 1u);
    }
    __syncthreads();
    if (tid < 256) {
      u32 sum = 0;
#pragma unroll
      for (int k = 0; k < 8; k++) sum += h8[k * 256 + tid];
      hist[tid] = sum;
    }
    __syncthreads();
    if (tid == 0) {
      u32 need = sh_need; int chosen = 0;
      for (int bb = 255; bb >= 0; bb--) {
        if (need <= hist[bb]) { chosen = bb; break; }
        need -= hist[bb];
      }
      sh_need = need;
      sh_prefix = (prefix << 8) | (u32)chosen;
    }
    __syncthreads();
  }
  u32 kth = sh_prefix;

  // compact all items with key >= kth (wave-aggregated atomic)
  for (int i0 = 0; i0 < KA; i0 += 1024) {
    int i = i0 + tid;
    u64 v = (i < KA) ? it[i] : 0ull;
    bool sel = (i < KA) && ((u32)(v >> 32) >= kth);
    u64 bal = __ballot(sel);
    u32 cnt = (u32)__popcll(bal);
    u32 base = 0;
    if (lane == 0 && cnt) base = atomicAdd(&sh_cnt, cnt);
    base = (u32)__shfl((int)base, 0, 64);
    if (sel) {
      u32 pos = base + (u32)__popcll(bal & ((1ull << lane) - 1ull));
      if (pos < 8192) arr[pos] = v;
    }
  }
  __syncthreads();
  u32 T = sh_cnt; if (T > 8192) T = 8192;
  for (int i = (int)T + tid; i < 8192; i += 1024) arr[i] = 0ull;

  // bitonic sort, descending; pair-indexed (4096 active pairs, no idle lanes)
  for (u32 k = 2; k <= 8192; k <<= 1) {
    for (u32 j = k >> 1; j > 0; j >>= 1) {
      __syncthreads();
#pragma unroll 4
      for (u32 m = tid; m < 4096; m += 1024) {
        u32 mm = m & (j - 1);
        u32 i = ((m - mm) << 1) + mm;
        u32 l = i + j;
        u64 a = arr[i], c = arr[l];
        bool dir = ((i & k) == 0);
        if ((a < c) == dir) { arr[i] = c; arr[l] = a; }
      }
    }
  }
  __syncthreads();
  for (int i = tid; i < N_PRE; i += 1024) {
    u64 v = arr[i];
    sitems[(size_t)b * N_PRE + i] = v;
    u32 kk = ~(u32)(v & 0xffffffffull);
    float4 bx = make_float4(0, 0, 0, 0);
    if (kk < KA) bx = roi[(size_t)b * KA + kk];
    sbox[(size_t)b * N_PRE + i] = bx;
  }
}

// ---------------- NMS suppression bitmask (upper-triangle 64x64 blocks) ----------------
__global__ __launch_bounds__(64) void k_mask(const float4* __restrict__ sbox,
    u64* __restrict__ mask, u64* __restrict__ diag) {
  const int cb = blockIdx.x, rb = blockIdx.y, b = blockIdx.z;
  if (cb < rb) return;
  const int tid = threadIdx.x;
  __shared__ float4 cbx[64];
  __shared__ float carea[64];
  int col0 = cb * 64;
  int c = col0 + tid;
  float4 v = (c < N_PRE) ? sbox[(size_t)b * N_PRE + c] : make_float4(0, 0, 0, 0);
  cbx[tid] = v;
  carea[tid] = (v.z - v.x) * (v.w - v.y);
  __syncthreads();
  int row = rb * 64 + tid;
  if (row >= N_PRE) return;
  float4 r = sbox[(size_t)b * N_PRE + row];
  float rarea = (r.z - r.x) * (r.w - r.y);
  u64 word = 0ull;
  for (int j = 0; j < 64; j++) {
    int cc = col0 + j;
    if (cc > row && cc < N_PRE) {
      float4 q = cbx[j];
      float ty = fmaxf(r.x, q.x), tx = fmaxf(r.y, q.y);
      float by = fminf(r.z, q.z), bx = fminf(r.w, q.w);
      float ihh = fmaxf(by - ty, 0.f), iww = fmaxf(bx - tx, 0.f);
      float inter = ihh * iww;
      float iou = inter / (rarea + carea[j] - inter + 1e-9f);
      if (iou > NMS_T) word |= (1ull << j);
    }
  }
  mask[((size_t)b * N_PRE + row) * NWORDS + cb] = word;
  if (cb == rb) diag[(size_t)b * N_PRE + row] = word;  // own-group suppression word
}

// ---------------- sequential NMS reduce (4-deep chained via diag) + outputs ----------------
__global__ __launch_bounds__(64) void k_nms_out(const u64* __restrict__ sitems,
    const float4* __restrict__ sbox, const u64* __restrict__ mask,
    const u64* __restrict__ diag, float* __restrict__ out) {
  const int b = blockIdx.x;
  const int lane = threadIdx.x;
  __shared__ u64 remv[NWORDS];
  __shared__ u64 pre[NWORDS];
  __shared__ u64 dia[N_PRE];
  __shared__ u32 keep[N_POST];
  for (int i = lane; i < NWORDS; i += 64) { remv[i] = 0ull; pre[i] = 0ull; }
  __syncthreads();
  u32 keyneg = ~__float_as_uint(NEGV);
  for (int i = lane; i < N_PRE; i += 64) {
    dia[i] = diag[(size_t)b * N_PRE + i];
    u32 key = (u32)(sitems[(size_t)b * N_PRE + i] >> 32);
    if (key == keyneg || key == 0u)
      atomicOr(&pre[i >> 6], 1ull << (i & 63));
  }
  if (lane == 0) pre[NWORDS - 1] |= ~((1ull << (N_PRE - 64 * (NWORDS - 1))) - 1ull);
  __syncthreads();

  int kc = 0;
  for (int g = 0; g < NWORDS && kc < N_POST; g++) {
    u64 done = 0ull;
    while (kc < N_POST) {
      u64 cur = remv[g] | pre[g] | done;
      if (cur == ~0ull) break;
      int r0 = -1, r1 = -1, r2 = -1, r3 = -1; int m = 1;
      u64 c2 = cur;
      int bit = __ffsll((long long)(~c2)) - 1;
      r0 = g * 64 + bit; c2 |= (1ull << bit) | dia[r0]; done |= 1ull << bit;
      if (c2 != ~0ull && kc + 1 < N_POST) {
        bit = __ffsll((long long)(~c2)) - 1;
        r1 = g * 64 + bit; c2 |= (1ull << bit) | dia[r1]; done |= 1ull << bit; m = 2;
        if (c2 != ~0ull && kc + 2 < N_POST) {
          bit = __ffsll((long long)(~c2)) - 1;
          r2 = g * 64 + bit; c2 |= (1ull << bit) | dia[r2]; done |= 1ull << bit; m = 3;
          if (c2 != ~0ull && kc + 3 < N_POST) {
            bit = __ffsll((long long)(~c2)) - 1;
            r3 = g * 64 + bit; c2 |= (1ull << bit) | dia[r3]; done |= 1ull << bit; m = 4;
          }
        }
      }
      if (lane == 0) {
        keep[kc] = (u32)r0;
        if (m > 1) keep[kc + 1] = (u32)r1;
        if (m > 2) keep[kc + 2] = (u32)r2;
        if (m > 3) keep[kc + 3] = (u32)r3;
      }
      int j = lane >> 4, l16 = lane & 15;
      int rj = (j == 0) ? r0 : (j == 1) ? r1 : (j == 2) ? r2 : r3;
      if (j < m) {
        const u64* mrow = mask + ((size_t)b * N_PRE + rj) * NWORDS;
        for (int cb = g + l16; cb < NWORDS; cb += 16)
          atomicOr(&remv[cb], mrow[cb]);
      }
      kc += m;
      __syncthreads();
    }
  }
  __syncthreads();
  for (int r = lane; r < N_POST; r += 64) {
    float4 bx = make_float4(0, 0, 0, 0);
    if (r < kc) bx = sbox[(size_t)b * N_PRE + keep[r]];
    ((float4*)out)[OFF_ROIS / 4 + (size_t)b * N_POST + r] = bx;
    out[OFF_RIDX + (size_t)b * N_POST + r] = (float)b;
  }
}

// ---------------- launch ----------------
extern "C" void kernel_launch(void* const* d_in, const int* in_sizes, int n_in,
                              void* d_out, int out_size, void* d_ws, size_t ws_size,
                              hipStream_t stream) {
  const float* x   = (const float*)d_in[0];
  const float* c1w = (const float*)d_in[1];
  const float* c1b = (const float*)d_in[2];
  const float* sw  = (const float*)d_in[3];
  const float* sb  = (const float*)d_in[4];
  const float* lw  = (const float*)d_in[5];
  const float* lb  = (const float*)d_in[6];
  const int* ih    = (const int*)d_in[7];
  const int* iw    = (const int*)d_in[8];
  float* out = (float*)d_out;
  char* wsb = (char*)d_ws;

  float* hid   = (float*)(wsb + WS_HID);
  float* fg    = (float*)(wsb + WS_FG);
  float4* roi  = (float4*)(wsb + WS_ROI);
  u64* items   = (u64*)(wsb + WS_ITEMS);
  u64* sitems  = (u64*)(wsb + WS_SITEMS);
  float4* sbox = (float4*)(wsb + WS_SBOX);
  u64* maskp   = (u64*)(wsb + WS_MASK);
  u64* diagp   = (u64*)(wsb + WS_DIAG);
  float* wT2   = (float*)(wsb + WS_WT);

  hipLaunchKernelGGL(k_init, dim3(660), dim3(256), 0, stream, c1w, wT2, out);
  hipLaunchKernelGGL(k_conv1, dim3(4, 25, 2), dim3(256), 0, stream, x, wT2, c1b, hid);
  hipLaunchKernelGGL(k_head, dim3((N_BATCH * NPIX + 255) / 256), dim3(256), 0, stream,
                     hid, sw, sb, lw, lb, out, fg);
  hipLaunchKernelGGL(k_prep, dim3((N_BATCH * KA + 255) / 256), dim3(256), 0, stream,
                     out, fg, ih, iw, roi, items);
  hipLaunchKernelGGL(k_select, dim3(2), dim3(1024), 0, stream, items, roi, sitems, sbox);
  hipLaunchKernelGGL(k_mask, dim3(NWORDS, NWORDS, 2), dim3(64), 0, stream, sbox, maskp, diagp);
  hipLaunchKernelGGL(k_nms_out, dim3(2), dim3(64), 0, stream, sitems, sbox, maskp, diagp, out);
}

// Round 7
// 1181.903 us; speedup vs baseline: 3.4406x; 1.1637x over previous
//
#include <hip/hip_runtime.h>
#include <hip/hip_bf16.h>
#include <math.h>

// ---------------- problem constants ----------------
#define N_BATCH 2
#define HH 50
#define WW 84
#define NPIX (HH*WW)           // 4200
#define KA (NPIX*9)            // 37800
#define N_PRE 6000
#define N_POST 300
#define NMS_T 0.7f
#define NEGV (-1e9f)
#define NWORDS 94              // ceil(6000/64)

// d_out offsets (floats)
#define OFF_LOCS   0
#define OFF_SCORES (N_BATCH*KA*4)                  // 302400
#define OFF_ROIS   (OFF_SCORES + N_BATCH*KA*2)     // 453600
#define OFF_RIDX   (OFF_ROIS + N_BATCH*N_POST*4)   // 456000
#define OFF_ANCH   (OFF_RIDX + N_BATCH*N_POST)     // 456600

// ws offsets (bytes), all 16B aligned
#define WS_HID    0ull          // p0 partial -> hid (in-place combine), 17203200 B
#define WS_ROI    17505600ull
#define WS_ITEMS  18715200ull
#define WS_SITEMS 19320000ull
#define WS_SBOX   19416000ull
#define WS_MASK   19608000ull
#define WS_DIAG   28632000ull   // 2*6000*8 = 96000 B
#define WS_PEXT   28824000ull   // extra conv partials p1..p3 (17203200 B each)
// wT2 (9.44 MB) parked at WS_ITEMS during k_init/k_conv1 (dead before k_head
// writes items / k_select writes sitems/sbox / k_mask writes mask).
#define WS_WT     WS_ITEMS
#define PART_BYTES 17203200ull

typedef unsigned long long u64;
typedef unsigned u32;

// ---------------- init: weight shuffle ----------------
// wT2[(t*4+ocb)*4608 + ((kx*3+ky)*4+ic)*128 + ocl] =
//   w[(ocb*128+ocl)*4608 + t*36 + ic*9+ky*3+kx]
__global__ __launch_bounds__(256) void k_init(const float* __restrict__ w,
    float* __restrict__ wT2) {
  __shared__ float ls[128][37];
  const int b = blockIdx.x;
  const int tid = threadIdx.x;
  const int t = b >> 2, ocb = b & 3;
  for (int j = 0; j < 18; j++) {
    int idx = tid + j * 256;           // 0..4607
    int oc = idx / 36, r = idx % 36;
    ls[oc][r] = w[(size_t)(ocb * 128 + oc) * 4608 + t * 36 + r];
  }
  __syncthreads();
  float* outp = wT2 + (size_t)(t * 4 + ocb) * 4608;
  for (int j = 0; j < 18; j++) {
    int idx = tid + j * 256;
    int s36 = idx / 128, oc = idx % 128;
    int q = s36 >> 2, ic = s36 & 3;
    int kx = q / 3, ky = q % 3;
    outp[idx] = ls[oc][ic * 9 + ky * 3 + kx];
  }
}

// ---------------- conv1 3x3 512->512 (partial over ics_per channels) --------
// 256 thr = 128 oc x 2 rows x 84 px; thread = 4 oc x 21 px (84 acc).
// grid (4, 25, 2*nsplit): z = icq*2 + n. Each block sums ics [icq*ics_per, +ics_per)
// into its partial buffer (no bias/relu). nsplit=4 -> 800 blocks -> 3 blocks/CU
// co-resident (3 waves/SIMD) -> dependency stalls hidden by TLP.
#define IC_T 4
__global__ __launch_bounds__(256) void k_conv1(const float* __restrict__ x,
    const float* __restrict__ wT2,
    float* __restrict__ p0, float* __restrict__ p1,
    float* __restrict__ p2, float* __restrict__ p3,
    int ics_per) {
  const int ocb  = blockIdx.x;   // 0..3
  const int rowb = blockIdx.y;   // 0..24
  const int icq  = blockIdx.z >> 1;
  const int n    = blockIdx.z & 1;
  const int tid  = threadIdx.x;
  const int g    = tid & 3;          // px group (21 px)
  const int tr   = (tid >> 2) & 1;   // row within block
  const int ocl  = tid >> 3;         // 0..31 (4 oc each)
  const int row0 = rowb * 2;
  const int ics0 = icq * ics_per;
  const int tiles = ics_per / IC_T;

  __shared__ __align__(16) float lx[IC_T * 4 * 96];   // 6KB
  __shared__ __align__(16) float lw[IC_T * 9 * 128];  // 18.4KB

  const float* xg = x + ((size_t)n * 512 + ics0) * NPIX;

  // x staging map: 1536 floats, 6/thread
  int goff[6];
#pragma unroll
  for (int j = 0; j < 6; j++) {
    int idx = tid + j * 256;
    int ic = idx / 384; int rem = idx % 384;
    int rr = rem / 96;  int rem2 = rem % 96;
    int g2 = rem2 / 24; int q = rem2 % 24;
    int grow = row0 - 1 + rr;
    int gcol = g2 * 21 - 1 + q;
    bool v = ((unsigned)grow < 50u) && ((unsigned)gcol < 84u);
    goff[j] = v ? (ic * NPIX + grow * 84 + gcol) : -1;
  }

  float acc[4][21];
#pragma unroll
  for (int i = 0; i < 4; i++)
#pragma unroll
    for (int p = 0; p < 21; p++) acc[i][p] = 0.f;

  float xs[6], wsv[18];
  const float* wt0 = wT2 + ((size_t)(ics0 >> 2) * 4 + ocb) * 4608;
  // prologue: stage tile 0
#pragma unroll
  for (int j = 0; j < 6; j++) xs[j] = (goff[j] >= 0) ? xg[goff[j]] : 0.f;
#pragma unroll
  for (int j = 0; j < 18; j++) wsv[j] = wt0[tid + j * 256];

  for (int t = 0; t < tiles; t++) {
    // commit staged regs to LDS
#pragma unroll
    for (int j = 0; j < 6; j++) lx[tid + j * 256] = xs[j];
#pragma unroll
    for (int j = 0; j < 18; j++) lw[tid + j * 256] = wsv[j];
    __syncthreads();

    // issue next tile's loads (hidden under compute)
    if (t < tiles - 1) {
      int xadv = (t + 1) * IC_T * NPIX;
      const float* wtn = wt0 + (size_t)(t + 1) * 4 * 4608;
#pragma unroll
      for (int j = 0; j < 6; j++) xs[j] = (goff[j] >= 0) ? xg[goff[j] + xadv] : 0.f;
#pragma unroll
      for (int j = 0; j < 18; j++) wsv[j] = wtn[tid + j * 256];
    }

    // compute current tile
#pragma unroll
    for (int ic = 0; ic < IC_T; ic++) {
#pragma unroll
      for (int ky = 0; ky < 3; ky++) {
        float xv[24];
        const float* lp = &lx[ic * 384 + (tr + ky) * 96 + g * 24];
#pragma unroll
        for (int v4 = 0; v4 < 6; v4++) {
          float4 f = *(const float4*)&lp[v4 * 4];
          xv[v4 * 4 + 0] = f.x; xv[v4 * 4 + 1] = f.y;
          xv[v4 * 4 + 2] = f.z; xv[v4 * 4 + 3] = f.w;
        }
#pragma unroll
        for (int kx = 0; kx < 3; kx++) {
          float4 wv = *(const float4*)&lw[((kx * 3 + ky) * IC_T + ic) * 128 + ocl * 4];
          float wa[4] = {wv.x, wv.y, wv.z, wv.w};
#pragma unroll
          for (int i = 0; i < 4; i++)
#pragma unroll
            for (int p = 0; p < 21; p++)
              acc[i][p] = fmaf(wa[i], xv[p + kx], acc[i][p]);
        }
      }
    }
    __syncthreads();
  }

  {
    float* hp = (icq == 0) ? p0 : (icq == 1) ? p1 : (icq == 2) ? p2 : p3;
    int oc = ocb * 128 + ocl * 4;
    int prow = row0 + tr;
#pragma unroll
    for (int i = 0; i < 4; i++) {
      float* op = &hp[(size_t)(n * 512 + oc + i) * NPIX + prow * 84 + g * 21];
#pragma unroll
      for (int p = 0; p < 21; p++) op[p] = acc[i][p];
    }
  }
}

// ---------------- combine partials: hid = relu(sum parts + bias) ------------
__global__ __launch_bounds__(256) void k_combine(float* __restrict__ p0,
    const float* __restrict__ p1, const float* __restrict__ p2,
    const float* __restrict__ p3, const float* __restrict__ bias, int nsplit) {
  const int T = 1075200;  // 2*512*4200/4 float4s (4200%4==0: no oc crossing)
  int idx = blockIdx.x * 256 + threadIdx.x;   // grid 1050*256 = 268800
  for (int i4 = idx; i4 < T; i4 += 268800) {
    float4 v = ((const float4*)p0)[i4];
    if (nsplit > 1) {
      float4 a = ((const float4*)p1)[i4];
      v.x += a.x; v.y += a.y; v.z += a.z; v.w += a.w;
      if (nsplit > 2) {
        float4 b2 = ((const float4*)p2)[i4];
        v.x += b2.x; v.y += b2.y; v.z += b2.z; v.w += b2.w;
        float4 c = ((const float4*)p3)[i4];
        v.x += c.x; v.y += c.y; v.z += c.z; v.w += c.w;
      }
    }
    float bv = bias[(i4 / 1050) & 511];
    v.x = fmaxf(v.x + bv, 0.f); v.y = fmaxf(v.y + bv, 0.f);
    v.z = fmaxf(v.z + bv, 0.f); v.w = fmaxf(v.w + bv, 0.f);
    ((float4*)p0)[i4] = v;
  }
}

// ---------------- heads (1x1 convs) + softmax + anchors + roi-prep fused ----
// 66 blocks x 256 thr = 128 px x 2 output-halves (27 outputs each).
__global__ __launch_bounds__(256) void k_head(const float* __restrict__ hid,
    const float* __restrict__ sw, const float* __restrict__ sb,
    const float* __restrict__ lww, const float* __restrict__ lb,
    const int* __restrict__ ihp, const int* __restrict__ iwp,
    float* __restrict__ out, float4* __restrict__ roi, u64* __restrict__ items) {
  const int tid = threadIdx.x;
  const int half = tid >> 7;         // 0,1
  const int pxl = tid & 127;
  const int P = blockIdx.x * 128 + pxl;
  const bool valid = P < N_BATCH * NPIX;
  const int n = P / NPIX, p = P - n * NPIX;
  const int o0 = half * 27;
  __shared__ float xt[32][128];      // 16KB
  __shared__ float wt[32][56];       // 7KB
  __shared__ float llocs[128][37];   // 18.9KB

  float acc[27];
#pragma unroll
  for (int o = 0; o < 27; o++) acc[o] = 0.f;

  for (int c0 = 0; c0 < 512; c0 += 32) {
    for (int j = 0; j < 16; j++) {
      int idx = tid + j * 256;
      int c = idx >> 7, lp = idx & 127;
      int PP = blockIdx.x * 128 + lp;
      float v = 0.f;
      if (PP < N_BATCH * NPIX) {
        int nn = PP / NPIX, pp = PP - nn * NPIX;
        v = hid[(size_t)(nn * 512 + c0 + c) * NPIX + pp];
      }
      xt[c][lp] = v;
    }
    for (int i = tid; i < 32 * 54; i += 256) {
      int c = i / 54, o = i % 54;
      wt[c][o] = (o < 18) ? sw[o * 512 + c0 + c] : lww[(o - 18) * 512 + c0 + c];
    }
    __syncthreads();
#pragma unroll 4
    for (int c = 0; c < 32; c++) {
      float xv = xt[c][pxl];
      const float* wp = &wt[c][o0];
#pragma unroll
      for (int o = 0; o < 27; o++) acc[o] = fmaf(xv, wp[o], acc[o]);
    }
    __syncthreads();
  }

  float raw[18];
  if (valid) {
    if (half == 0) {
      // scores o=0..17 ; locs o'=0..8 (acc[18..26])
#pragma unroll
      for (int o = 0; o < 18; o++) raw[o] = acc[o] + sb[o];
      size_t sbase = OFF_SCORES + ((size_t)n * KA + (size_t)p * 9) * 2;
#pragma unroll
      for (int o = 0; o < 18; o++) out[sbase + o] = raw[o];
      size_t lbase = OFF_LOCS + ((size_t)n * KA + (size_t)p * 9) * 4;
#pragma unroll
      for (int j = 0; j < 9; j++) {
        float lv = acc[18 + j] + lb[j];
        out[lbase + j] = lv;
        llocs[pxl][j] = lv;
      }
    } else {
      // locs o'=9..35 (acc[0..26])
      size_t lbase = OFF_LOCS + ((size_t)n * KA + (size_t)p * 9) * 4;
#pragma unroll
      for (int j = 0; j < 27; j++) {
        float lv = acc[j] + lb[9 + j];
        out[lbase + 9 + j] = lv;
        llocs[pxl][9 + j] = lv;
      }
    }
  }
  __syncthreads();

  if (valid && half == 0) {
    const int pi = p / WW, pj = p - pi * WW;
    const float sy = (float)(pi * 16), sx = (float)(pj * 16);
    const float imh = (float)ihp[0], imw = (float)iwp[0];
#pragma unroll
    for (int a = 0; a < 9; a++) {
      int ri = a / 3, si = a % 3;
      double ratio = (ri == 0) ? 0.5 : ((ri == 1) ? 1.0 : 2.0);
      double scale = (si == 0) ? 8.0 : ((si == 1) ? 16.0 : 32.0);
      double hh = 16.0 * scale * sqrt(ratio);
      double ww = 16.0 * scale * sqrt(1.0 / ratio);
      float ay1 = (float)(8.0 - hh * 0.5), ax1 = (float)(8.0 - ww * 0.5);
      float ay2 = (float)(8.0 + hh * 0.5), ax2 = (float)(8.0 + ww * 0.5);
      float4 A = make_float4(sy + ay1, sx + ax1, sy + ay2, sx + ax2);
      int k = p * 9 + a;
      if (n == 0) ((float4*)out)[OFF_ANCH / 4 + k] = A;
      // softmax fg
      float r0 = raw[2 * a], r1 = raw[2 * a + 1];
      float m = fmaxf(r0, r1);
      float e0 = expf(r0 - m), e1 = expf(r1 - m);
      float fgv = e1 / (e0 + e1);
      // loc2bbox + clip + size filter + key
      float Lx = llocs[pxl][4 * a], Ly = llocs[pxl][4 * a + 1];
      float Lz = llocs[pxl][4 * a + 2], Lw = llocs[pxl][4 * a + 3];
      float h = A.z - A.x, w = A.w - A.y;
      float yc = A.x + 0.5f * h, xc = A.y + 0.5f * w;
      float cy = Lx * h + yc, cx = Ly * w + xc;
      float nh = expf(Lz) * h, nw = expf(Lw) * w;
      float y1 = cy - 0.5f * nh, x1 = cx - 0.5f * nw;
      float y2 = cy + 0.5f * nh, x2 = cx + 0.5f * nw;
      y1 = fminf(fmaxf(y1, 0.f), imh); y2 = fminf(fmaxf(y2, 0.f), imh);
      x1 = fminf(fmaxf(x1, 0.f), imw); x2 = fminf(fmaxf(x2, 0.f), imw);
      bool ok = ((y2 - y1) >= 16.f) && ((x2 - x1) >= 16.f);
      float sc = ok ? fgv : NEGV;
      u32 u = __float_as_uint(sc);
      u32 key = (u & 0x80000000u) ? ~u : (u | 0x80000000u);
      roi[(size_t)n * KA + k] = make_float4(y1, x1, y2, x2);
      items[(size_t)n * KA + k] = ((u64)key << 32) | (u32)(~(u32)k);
    }
  }
}

// ---------------- per-batch: radix-select top 6000 + bitonic sort ----------------
__global__ __launch_bounds__(1024) void k_select(const u64* __restrict__ items,
    const float4* __restrict__ roi, u64* __restrict__ sitems, float4* __restrict__ sbox) {
  const int b = blockIdx.x;
  const int tid = threadIdx.x;
  const int lane = tid & 63;
  const int slice = tid >> 7;        // 0..7 (2 waves per sub-hist)
  const u64* it = items + (size_t)b * KA;
  __shared__ u64 arr[8192];
  __shared__ u32 hist[256];
  __shared__ u32 sh_need, sh_prefix, sh_cnt;
  u32* h8 = (u32*)arr;               // 8*256 u32 sub-hists (dead before sort)
  if (tid == 0) { sh_need = N_PRE; sh_prefix = 0; sh_cnt = 0; }

  for (int s = 3; s >= 0; s--) {
    for (int i = tid; i < 2048; i += 1024) h8[i] = 0;
    __syncthreads();
    u32 prefix = sh_prefix;
    int t = 3 - s;
    for (int i = tid; i < KA; i += 1024) {
      u32 key = (u32)(it[i] >> 32);
      bool match = (t == 0) || ((key >> ((s + 1) * 8)) == prefix);
      if (match) atomicAdd(&h8[slice * 256 + ((key >> (s * 8)) & 255)], 1u);
    }
    __syncthreads();
    if (tid < 256) {
      u32 sum = 0;
#pragma unroll
      for (int k = 0; k < 8; k++) sum += h8[k * 256 + tid];
      hist[tid] = sum;
    }
    __syncthreads();
    if (tid == 0) {
      u32 need = sh_need; int chosen = 0;
      for (int bb = 255; bb >= 0; bb--) {
        if (need <= hist[bb]) { chosen = bb; break; }
        need -= hist[bb];
      }
      sh_need = need;
      sh_prefix = (prefix << 8) | (u32)chosen;
    }
    __syncthreads();
  }
  u32 kth = sh_prefix;

  // compact all items with key >= kth (wave-aggregated atomic)
  for (int i0 = 0; i0 < KA; i0 += 1024) {
    int i = i0 + tid;
    u64 v = (i < KA) ? it[i] : 0ull;
    bool sel = (i < KA) && ((u32)(v >> 32) >= kth);
    u64 bal = __ballot(sel);
    u32 cnt = (u32)__popcll(bal);
    u32 base = 0;
    if (lane == 0 && cnt) base = atomicAdd(&sh_cnt, cnt);
    base = (u32)__shfl((int)base, 0, 64);
    if (sel) {
      u32 pos = base + (u32)__popcll(bal & ((1ull << lane) - 1ull));
      if (pos < 8192) arr[pos] = v;
    }
  }
  __syncthreads();
  u32 T = sh_cnt; if (T > 8192) T = 8192;
  for (int i = (int)T + tid; i < 8192; i += 1024) arr[i] = 0ull;

  // bitonic sort, descending; pair-indexed (4096 active pairs, no idle lanes)
  for (u32 k = 2; k <= 8192; k <<= 1) {
    for (u32 j = k >> 1; j > 0; j >>= 1) {
      __syncthreads();
#pragma unroll 4
      for (u32 m = tid; m < 4096; m += 1024) {
        u32 mm = m & (j - 1);
        u32 i = ((m - mm) << 1) + mm;
        u32 l = i + j;
        u64 a = arr[i], c = arr[l];
        bool dir = ((i & k) == 0);
        if ((a < c) == dir) { arr[i] = c; arr[l] = a; }
      }
    }
  }
  __syncthreads();
  for (int i = tid; i < N_PRE; i += 1024) {
    u64 v = arr[i];
    sitems[(size_t)b * N_PRE + i] = v;
    u32 kk = ~(u32)(v & 0xffffffffull);
    float4 bx = make_float4(0, 0, 0, 0);
    if (kk < KA) bx = roi[(size_t)b * KA + kk];
    sbox[(size_t)b * N_PRE + i] = bx;
  }
}

// ---------------- NMS suppression bitmask (upper-triangle 64x64 blocks) ----------------
__global__ __launch_bounds__(64) void k_mask(const float4* __restrict__ sbox,
    u64* __restrict__ mask, u64* __restrict__ diag) {
  const int cb = blockIdx.x, rb = blockIdx.y, b = blockIdx.z;
  if (cb < rb) return;
  const int tid = threadIdx.x;
  __shared__ float4 cbx[64];
  __shared__ float carea[64];
  int col0 = cb * 64;
  int c = col0 + tid;
  float4 v = (c < N_PRE) ? sbox[(size_t)b * N_PRE + c] : make_float4(0, 0, 0, 0);
  cbx[tid] = v;
  carea[tid] = (v.z - v.x) * (v.w - v.y);
  __syncthreads();
  int row = rb * 64 + tid;
  if (row >= N_PRE) return;
  float4 r = sbox[(size_t)b * N_PRE + row];
  float rarea = (r.z - r.x) * (r.w - r.y);
  u64 word = 0ull;
  for (int j = 0; j < 64; j++) {
    int cc = col0 + j;
    if (cc > row && cc < N_PRE) {
      float4 q = cbx[j];
      float ty = fmaxf(r.x, q.x), tx = fmaxf(r.y, q.y);
      float by = fminf(r.z, q.z), bx = fminf(r.w, q.w);
      float ihh = fmaxf(by - ty, 0.f), iww = fmaxf(bx - tx, 0.f);
      float inter = ihh * iww;
      float iou = inter / (rarea + carea[j] - inter + 1e-9f);
      if (iou > NMS_T) word |= (1ull << j);
    }
  }
  mask[((size_t)b * N_PRE + row) * NWORDS + cb] = word;
  if (cb == rb) diag[(size_t)b * N_PRE + row] = word;  // own-group suppression word
}

// ---------------- sequential NMS reduce (4-deep chained via diag) + outputs ----------------
__global__ __launch_bounds__(64) void k_nms_out(const u64* __restrict__ sitems,
    const float4* __restrict__ sbox, const u64* __restrict__ mask,
    const u64* __restrict__ diag, float* __restrict__ out) {
  const int b = blockIdx.x;
  const int lane = threadIdx.x;
  __shared__ u64 remv[NWORDS];
  __shared__ u64 pre[NWORDS];
  __shared__ u64 dia[N_PRE];
  __shared__ u32 keep[N_POST];
  for (int i = lane; i < NWORDS; i += 64) { remv[i] = 0ull; pre[i] = 0ull; }
  __syncthreads();
  u32 keyneg = ~__float_as_uint(NEGV);
  for (int i = lane; i < N_PRE; i += 64) {
    dia[i] = diag[(size_t)b * N_PRE + i];
    u32 key = (u32)(sitems[(size_t)b * N_PRE + i] >> 32);
    if (key == keyneg || key == 0u)
      atomicOr(&pre[i >> 6], 1ull << (i & 63));
  }
  if (lane == 0) pre[NWORDS - 1] |= ~((1ull << (N_PRE - 64 * (NWORDS - 1))) - 1ull);
  __syncthreads();

  int kc = 0;
  for (int g = 0; g < NWORDS && kc < N_POST; g++) {
    u64 done = 0ull;
    while (kc < N_POST) {
      u64 cur = remv[g] | pre[g] | done;
      if (cur == ~0ull) break;
      int r0 = -1, r1 = -1, r2 = -1, r3 = -1; int m = 1;
      u64 c2 = cur;
      int bit = __ffsll((long long)(~c2)) - 1;
      r0 = g * 64 + bit; c2 |= (1ull << bit) | dia[r0]; done |= 1ull << bit;
      if (c2 != ~0ull && kc + 1 < N_POST) {
        bit = __ffsll((long long)(~c2)) - 1;
        r1 = g * 64 + bit; c2 |= (1ull << bit) | dia[r1]; done |= 1ull << bit; m = 2;
        if (c2 != ~0ull && kc + 2 < N_POST) {
          bit = __ffsll((long long)(~c2)) - 1;
          r2 = g * 64 + bit; c2 |= (1ull << bit) | dia[r2]; done |= 1ull << bit; m = 3;
          if (c2 != ~0ull && kc + 3 < N_POST) {
            bit = __ffsll((long long)(~c2)) - 1;
            r3 = g * 64 + bit; c2 |= (1ull << bit) | dia[r3]; done |= 1ull << bit; m = 4;
          }
        }
      }
      if (lane == 0) {
        keep[kc] = (u32)r0;
        if (m > 1) keep[kc + 1] = (u32)r1;
        if (m > 2) keep[kc + 2] = (u32)r2;
        if (m > 3) keep[kc + 3] = (u32)r3;
      }
      int j = lane >> 4, l16 = lane & 15;
      int rj = (j == 0) ? r0 : (j == 1) ? r1 : (j == 2) ? r2 : r3;
      if (j < m) {
        const u64* mrow = mask + ((size_t)b * N_PRE + rj) * NWORDS;
        for (int cb = g + l16; cb < NWORDS; cb += 16)
          atomicOr(&remv[cb], mrow[cb]);
      }
      kc += m;
      __syncthreads();
    }
  }
  __syncthreads();
  for (int r = lane; r < N_POST; r += 64) {
    float4 bx = make_float4(0, 0, 0, 0);
    if (r < kc) bx = sbox[(size_t)b * N_PRE + keep[r]];
    ((float4*)out)[OFF_ROIS / 4 + (size_t)b * N_POST + r] = bx;
    out[OFF_RIDX + (size_t)b * N_POST + r] = (float)b;
  }
}

// ---------------- launch ----------------
extern "C" void kernel_launch(void* const* d_in, const int* in_sizes, int n_in,
                              void* d_out, int out_size, void* d_ws, size_t ws_size,
                              hipStream_t stream) {
  const float* x   = (const float*)d_in[0];
  const float* c1w = (const float*)d_in[1];
  const float* c1b = (const float*)d_in[2];
  const float* sw  = (const float*)d_in[3];
  const float* sb  = (const float*)d_in[4];
  const float* lw  = (const float*)d_in[5];
  const float* lb  = (const float*)d_in[6];
  const int* ih    = (const int*)d_in[7];
  const int* iw    = (const int*)d_in[8];
  float* out = (float*)d_out;
  char* wsb = (char*)d_ws;

  float* hid   = (float*)(wsb + WS_HID);
  float4* roi  = (float4*)(wsb + WS_ROI);
  u64* items   = (u64*)(wsb + WS_ITEMS);
  u64* sitems  = (u64*)(wsb + WS_SITEMS);
  float4* sbox = (float4*)(wsb + WS_SBOX);
  u64* maskp   = (u64*)(wsb + WS_MASK);
  u64* diagp   = (u64*)(wsb + WS_DIAG);
  float* wT2   = (float*)(wsb + WS_WT);

  // split-K degree chosen by available workspace (deterministic per session)
  int nsplit = 1;
  if (ws_size >= WS_PEXT + 3 * PART_BYTES) nsplit = 4;
  else if (ws_size >= WS_PEXT + 1 * PART_BYTES) nsplit = 2;
  float* p1 = (nsplit > 1) ? (float*)(wsb + WS_PEXT) : hid;
  float* p2 = (nsplit > 2) ? (float*)(wsb + WS_PEXT + PART_BYTES) : hid;
  float* p3 = (nsplit > 2) ? (float*)(wsb + WS_PEXT + 2 * PART_BYTES) : hid;

  hipLaunchKernelGGL(k_init, dim3(512), dim3(256), 0, stream, c1w, wT2);
  hipLaunchKernelGGL(k_conv1, dim3(4, 25, 2 * nsplit), dim3(256), 0, stream,
                     x, wT2, hid, p1, p2, p3, 512 / nsplit);
  hipLaunchKernelGGL(k_combine, dim3(1050), dim3(256), 0, stream,
                     hid, p1, p2, p3, c1b, nsplit);
  hipLaunchKernelGGL(k_head, dim3(66), dim3(256), 0, stream,
                     hid, sw, sb, lw, lb, ih, iw, out, roi, items);
  hipLaunchKernelGGL(k_select, dim3(2), dim3(1024), 0, stream, items, roi, sitems, sbox);
  hipLaunchKernelGGL(k_mask, dim3(NWORDS, NWORDS, 2), dim3(64), 0, stream, sbox, maskp, diagp);
  hipLaunchKernelGGL(k_nms_out, dim3(2), dim3(64), 0, stream, sitems, sbox, maskp, diagp, out);
}

// Round 8
// 1165.257 us; speedup vs baseline: 3.4898x; 1.0143x over previous
//
#include <hip/hip_runtime.h>
#include <hip/hip_bf16.h>
#include <math.h>

// ---------------- problem constants ----------------
#define N_BATCH 2
#define HH 50
#define WW 84
#define NPIX (HH*WW)           // 4200
#define KA (NPIX*9)            // 37800
#define N_PRE 6000
#define N_POST 300
#define NMS_T 0.7f
#define NEGV (-1e9f)
#define NWORDS 94              // ceil(6000/64)

// d_out offsets (floats)
#define OFF_LOCS   0
#define OFF_SCORES (N_BATCH*KA*4)                  // 302400
#define OFF_ROIS   (OFF_SCORES + N_BATCH*KA*2)     // 453600
#define OFF_RIDX   (OFF_ROIS + N_BATCH*N_POST*4)   // 456000
#define OFF_ANCH   (OFF_RIDX + N_BATCH*N_POST)     // 456600

// ws offsets (bytes), all 16B aligned
#define WS_HID    0ull          // p0 partial -> hid (in-place combine), 17203200 B
#define WS_ROI    17505600ull
#define WS_ITEMS  18715200ull
#define WS_SITEMS 19320000ull
#define WS_SBOX   19416000ull
#define WS_MASK   19608000ull
#define WS_DIAG   28632000ull   // 2*6000*8 = 96000 B
#define WS_PEXT   28824000ull   // extra conv partials p1..p3 (17203200 B each)
// wT3 (9.44 MB) parked at WS_ITEMS during k_init/k_conv1 (dead before k_head
// writes items / k_select writes sitems/sbox / k_mask writes mask).
#define WS_WT     WS_ITEMS
#define PART_BYTES 17203200ull

typedef unsigned long long u64;
typedef unsigned u32;

// ---------------- init: weight shuffle ----------------
// wT3[(t2*8+ocb)*1152 + ((kx*3+ky)*2+icl)*64 + ocl] =
//   w[(ocb*64+ocl)*4608 + (t2*2+icl)*9 + ky*3 + kx]
// grid (256 t2, 8 ocb), 64 thr.
__global__ __launch_bounds__(64) void k_init(const float* __restrict__ w,
    float* __restrict__ wT3) {
  __shared__ float ls[64][19];
  const int t2 = blockIdx.x, ocb = blockIdx.y;
  const int tid = threadIdx.x;
#pragma unroll
  for (int j = 0; j < 18; j++) {
    int idx = tid + j * 64;            // 0..1151
    int oc = idx / 18, r = idx % 18;
    ls[oc][r] = w[(size_t)(ocb * 64 + oc) * 4608 + t2 * 18 + r];
  }
  __syncthreads();
  float* outp = wT3 + (size_t)(t2 * 8 + ocb) * 1152;
#pragma unroll
  for (int j = 0; j < 18; j++) {
    int idx = tid + j * 64;
    int q = idx / 64, oc = idx % 64;
    int kxky = q >> 1, icl = q & 1;
    int kx = kxky / 3, ky = kxky % 3;
    outp[idx] = ls[oc][icl * 9 + ky * 3 + kx];
  }
}

// ---------------- conv1 3x3 512->512 (partial over ics_per channels) --------
// 64-thr single-wave block = 64 oc x 1 row x 84 px; thread = 4 oc x 21 px.
// grid (8, 50, 2*nsplit) = 3200 @ nsplit4 -> ~12.5 blocks/CU streaming,
// 8 resident (VGPR<=256) -> 2 waves/SIMD; 1-wave barriers are cheap.
// FMA order (ic,ky,kx,oc,px) identical to prior rounds -> bit-exact.
#define IC_T 2
__global__ __launch_bounds__(64, 2) void k_conv1(const float* __restrict__ x,
    const float* __restrict__ wT3,
    float* __restrict__ p0, float* __restrict__ p1,
    float* __restrict__ p2, float* __restrict__ p3,
    int ics_per) {
  const int ocb = blockIdx.x;   // 0..7 (64 oc)
  const int row = blockIdx.y;   // 0..49
  const int icq = blockIdx.z >> 1;
  const int n   = blockIdx.z & 1;
  const int tid = threadIdx.x;  // 0..63
  const int g   = tid & 3;      // px group (21 px)
  const int ocl = tid >> 2;     // 0..15 (4 oc each)
  const int ics0 = icq * ics_per;
  const int tiles = ics_per / IC_T;

  __shared__ __align__(16) float lx[IC_T * 3 * 96];   // 2.3KB
  __shared__ __align__(16) float lw[IC_T * 9 * 64];   // 4.6KB

  const float* xg = x + ((size_t)n * 512 + ics0) * NPIX;

  // x staging map: 576 floats, 9/thread
  int goff[9];
#pragma unroll
  for (int j = 0; j < 9; j++) {
    int idx = tid + j * 64;
    int ic = idx / 288; int rem = idx % 288;
    int rr = rem / 96;  int rem2 = rem % 96;
    int g2 = rem2 / 24; int q = rem2 % 24;
    int grow = row - 1 + rr;
    int gcol = g2 * 21 - 1 + q;
    bool v = ((unsigned)grow < 50u) && ((unsigned)gcol < 84u);
    goff[j] = v ? (ic * NPIX + grow * 84 + gcol) : -1;
  }

  float acc[4][21];
#pragma unroll
  for (int i = 0; i < 4; i++)
#pragma unroll
    for (int p = 0; p < 21; p++) acc[i][p] = 0.f;

  float xs[9], wsv[18];
  const float* wt0 = wT3 + ((size_t)(ics0 >> 1) * 8 + ocb) * 1152;
  // prologue: stage tile 0
#pragma unroll
  for (int j = 0; j < 9; j++) xs[j] = (goff[j] >= 0) ? xg[goff[j]] : 0.f;
#pragma unroll
  for (int j = 0; j < 18; j++) wsv[j] = wt0[tid + j * 64];

  for (int t = 0; t < tiles; t++) {
    // commit staged regs to LDS
#pragma unroll
    for (int j = 0; j < 9; j++) lx[tid + j * 64] = xs[j];
#pragma unroll
    for (int j = 0; j < 18; j++) lw[tid + j * 64] = wsv[j];
    __syncthreads();

    // issue next tile's loads (hidden under compute)
    if (t < tiles - 1) {
      int xadv = (t + 1) * IC_T * NPIX;
      const float* wtn = wt0 + (size_t)(t + 1) * 9216;
#pragma unroll
      for (int j = 0; j < 9; j++) xs[j] = (goff[j] >= 0) ? xg[goff[j] + xadv] : 0.f;
#pragma unroll
      for (int j = 0; j < 18; j++) wsv[j] = wtn[tid + j * 64];
    }

    // compute current tile (ic,ky,kx,oc,px nesting preserved)
#pragma unroll
    for (int icl = 0; icl < IC_T; icl++) {
#pragma unroll
      for (int ky = 0; ky < 3; ky++) {
        float xv[24];
        const float* lp = &lx[icl * 288 + ky * 96 + g * 24];
#pragma unroll
        for (int v4 = 0; v4 < 6; v4++) {
          float4 f = *(const float4*)&lp[v4 * 4];
          xv[v4 * 4 + 0] = f.x; xv[v4 * 4 + 1] = f.y;
          xv[v4 * 4 + 2] = f.z; xv[v4 * 4 + 3] = f.w;
        }
#pragma unroll
        for (int kx = 0; kx < 3; kx++) {
          float4 wv = *(const float4*)&lw[((kx * 3 + ky) * IC_T + icl) * 64 + ocl * 4];
          float wa[4] = {wv.x, wv.y, wv.z, wv.w};
#pragma unroll
          for (int i = 0; i < 4; i++)
#pragma unroll
            for (int p = 0; p < 21; p++)
              acc[i][p] = fmaf(wa[i], xv[p + kx], acc[i][p]);
        }
      }
    }
    __syncthreads();
  }

  {
    float* hp = (icq == 0) ? p0 : (icq == 1) ? p1 : (icq == 2) ? p2 : p3;
    int oc = ocb * 64 + ocl * 4;
#pragma unroll
    for (int i = 0; i < 4; i++) {
      float* op = &hp[(size_t)(n * 512 + oc + i) * NPIX + row * 84 + g * 21];
#pragma unroll
      for (int p = 0; p < 21; p++) op[p] = acc[i][p];
    }
  }
}

// ---------------- combine partials: hid = relu(sum parts + bias) ------------
__global__ __launch_bounds__(256) void k_combine(float* __restrict__ p0,
    const float* __restrict__ p1, const float* __restrict__ p2,
    const float* __restrict__ p3, const float* __restrict__ bias, int nsplit) {
  const int T = 1075200;  // 2*512*4200/4 float4s (4200%4==0: no oc crossing)
  int idx = blockIdx.x * 256 + threadIdx.x;   // grid 1050*256 = 268800
  for (int i4 = idx; i4 < T; i4 += 268800) {
    float4 v = ((const float4*)p0)[i4];
    if (nsplit > 1) {
      float4 a = ((const float4*)p1)[i4];
      v.x += a.x; v.y += a.y; v.z += a.z; v.w += a.w;
      if (nsplit > 2) {
        float4 b2 = ((const float4*)p2)[i4];
        v.x += b2.x; v.y += b2.y; v.z += b2.z; v.w += b2.w;
        float4 c = ((const float4*)p3)[i4];
        v.x += c.x; v.y += c.y; v.z += c.z; v.w += c.w;
      }
    }
    float bv = bias[(i4 / 1050) & 511];
    v.x = fmaxf(v.x + bv, 0.f); v.y = fmaxf(v.y + bv, 0.f);
    v.z = fmaxf(v.z + bv, 0.f); v.w = fmaxf(v.w + bv, 0.f);
    ((float4*)p0)[i4] = v;
  }
}

// ---------------- heads (1x1 convs) + softmax + anchors + roi-prep fused ----
// 66 blocks x 256 thr = 128 px x 2 output-halves (27 outputs each).
__global__ __launch_bounds__(256) void k_head(const float* __restrict__ hid,
    const float* __restrict__ sw, const float* __restrict__ sb,
    const float* __restrict__ lww, const float* __restrict__ lb,
    const int* __restrict__ ihp, const int* __restrict__ iwp,
    float* __restrict__ out, float4* __restrict__ roi, u64* __restrict__ items) {
  const int tid = threadIdx.x;
  const int half = tid >> 7;         // 0,1
  const int pxl = tid & 127;
  const int P = blockIdx.x * 128 + pxl;
  const bool valid = P < N_BATCH * NPIX;
  const int n = P / NPIX, p = P - n * NPIX;
  const int o0 = half * 27;
  __shared__ float xt[32][128];      // 16KB
  __shared__ float wt[32][56];       // 7KB
  __shared__ float llocs[128][37];   // 18.9KB

  float acc[27];
#pragma unroll
  for (int o = 0; o < 27; o++) acc[o] = 0.f;

  for (int c0 = 0; c0 < 512; c0 += 32) {
    for (int j = 0; j < 16; j++) {
      int idx = tid + j * 256;
      int c = idx >> 7, lp = idx & 127;
      int PP = blockIdx.x * 128 + lp;
      float v = 0.f;
      if (PP < N_BATCH * NPIX) {
        int nn = PP / NPIX, pp = PP - nn * NPIX;
        v = hid[(size_t)(nn * 512 + c0 + c) * NPIX + pp];
      }
      xt[c][lp] = v;
    }
    for (int i = tid; i < 32 * 54; i += 256) {
      int c = i / 54, o = i % 54;
      wt[c][o] = (o < 18) ? sw[o * 512 + c0 + c] : lww[(o - 18) * 512 + c0 + c];
    }
    __syncthreads();
#pragma unroll 4
    for (int c = 0; c < 32; c++) {
      float xv = xt[c][pxl];
      const float* wp = &wt[c][o0];
#pragma unroll
      for (int o = 0; o < 27; o++) acc[o] = fmaf(xv, wp[o], acc[o]);
    }
    __syncthreads();
  }

  float raw[18];
  if (valid) {
    if (half == 0) {
      // scores o=0..17 ; locs o'=0..8 (acc[18..26])
#pragma unroll
      for (int o = 0; o < 18; o++) raw[o] = acc[o] + sb[o];
      size_t sbase = OFF_SCORES + ((size_t)n * KA + (size_t)p * 9) * 2;
#pragma unroll
      for (int o = 0; o < 18; o++) out[sbase + o] = raw[o];
      size_t lbase = OFF_LOCS + ((size_t)n * KA + (size_t)p * 9) * 4;
#pragma unroll
      for (int j = 0; j < 9; j++) {
        float lv = acc[18 + j] + lb[j];
        out[lbase + j] = lv;
        llocs[pxl][j] = lv;
      }
    } else {
      // locs o'=9..35 (acc[0..26])
      size_t lbase = OFF_LOCS + ((size_t)n * KA + (size_t)p * 9) * 4;
#pragma unroll
      for (int j = 0; j < 27; j++) {
        float lv = acc[j] + lb[9 + j];
        out[lbase + 9 + j] = lv;
        llocs[pxl][9 + j] = lv;
      }
    }
  }
  __syncthreads();

  if (valid && half == 0) {
    const int pi = p / WW, pj = p - pi * WW;
    const float sy = (float)(pi * 16), sx = (float)(pj * 16);
    const float imh = (float)ihp[0], imw = (float)iwp[0];
#pragma unroll
    for (int a = 0; a < 9; a++) {
      int ri = a / 3, si = a % 3;
      double ratio = (ri == 0) ? 0.5 : ((ri == 1) ? 1.0 : 2.0);
      double scale = (si == 0) ? 8.0 : ((si == 1) ? 16.0 : 32.0);
      double hh = 16.0 * scale * sqrt(ratio);
      double ww = 16.0 * scale * sqrt(1.0 / ratio);
      float ay1 = (float)(8.0 - hh * 0.5), ax1 = (float)(8.0 - ww * 0.5);
      float ay2 = (float)(8.0 + hh * 0.5), ax2 = (float)(8.0 + ww * 0.5);
      float4 A = make_float4(sy + ay1, sx + ax1, sy + ay2, sx + ax2);
      int k = p * 9 + a;
      if (n == 0) ((float4*)out)[OFF_ANCH / 4 + k] = A;
      // softmax fg
      float r0 = raw[2 * a], r1 = raw[2 * a + 1];
      float m = fmaxf(r0, r1);
      float e0 = expf(r0 - m), e1 = expf(r1 - m);
      float fgv = e1 / (e0 + e1);
      // loc2bbox + clip + size filter + key
      float Lx = llocs[pxl][4 * a], Ly = llocs[pxl][4 * a + 1];
      float Lz = llocs[pxl][4 * a + 2], Lw = llocs[pxl][4 * a + 3];
      float h = A.z - A.x, w = A.w - A.y;
      float yc = A.x + 0.5f * h, xc = A.y + 0.5f * w;
      float cy = Lx * h + yc, cx = Ly * w + xc;
      float nh = expf(Lz) * h, nw = expf(Lw) * w;
      float y1 = cy - 0.5f * nh, x1 = cx - 0.5f * nw;
      float y2 = cy + 0.5f * nh, x2 = cx + 0.5f * nw;
      y1 = fminf(fmaxf(y1, 0.f), imh); y2 = fminf(fmaxf(y2, 0.f), imh);
      x1 = fminf(fmaxf(x1, 0.f), imw); x2 = fminf(fmaxf(x2, 0.f), imw);
      bool ok = ((y2 - y1) >= 16.f) && ((x2 - x1) >= 16.f);
      float sc = ok ? fgv : NEGV;
      u32 u = __float_as_uint(sc);
      u32 key = (u & 0x80000000u) ? ~u : (u | 0x80000000u);
      roi[(size_t)n * KA + k] = make_float4(y1, x1, y2, x2);
      items[(size_t)n * KA + k] = ((u64)key << 32) | (u32)(~(u32)k);
    }
  }
}

// ---------------- per-batch: radix-select top 6000 + bitonic sort ----------------
__global__ __launch_bounds__(1024) void k_select(const u64* __restrict__ items,
    const float4* __restrict__ roi, u64* __restrict__ sitems, float4* __restrict__ sbox) {
  const int b = blockIdx.x;
  const int tid = threadIdx.x;
  const int lane = tid & 63;
  const int slice = tid & 7;         // per-lane sub-hist spread (hot-bin /8)
  const u64* it = items + (size_t)b * KA;
  __shared__ u64 arr[8192];
  __shared__ u32 hist[256];
  __shared__ u32 sh_need, sh_prefix, sh_cnt;
  u32* h8 = (u32*)arr;               // 8*256 u32 sub-hists (dead before sort)
  if (tid == 0) { sh_need = N_PRE; sh_prefix = 0; sh_cnt = 0; }

  for (int s = 3; s >= 0; s--) {
    for (int i = tid; i < 2048; i += 1024) h8[i] = 0;
    __syncthreads();
    u32 prefix = sh_prefix;
    int t = 3 - s;
    for (int i = tid; i < KA; i += 1024) {
      u32 key = (u32)(it[i] >> 32);
      bool match = (t == 0) || ((key >> ((s + 1) * 8)) == prefix);
      if (match) atomicAdd(&h8[slice * 256 + ((key >> (s * 8)) & 255)], 1u);
    }
    __syncthreads();
    if (tid < 256) {
      u32 sum = 0;
#pragma unroll
      for (int k = 0; k < 8; k++) sum += h8[k * 256 + tid];
      hist[tid] = sum;
    }
    __syncthreads();
    if (tid == 0) {
      u32 need = sh_need; int chosen = 0;
      for (int bb = 255; bb >= 0; bb--) {
        if (need <= hist[bb]) { chosen = bb; break; }
        need -= hist[bb];
      }
      sh_need = need;
      sh_prefix = (prefix << 8) | (u32)chosen;
    }
    __syncthreads();
  }
  u32 kth = sh_prefix;

  // compact all items with key >= kth (wave-aggregated atomic)
  for (int i0 = 0; i0 < KA; i0 += 1024) {
    int i = i0 + tid;
    u64 v = (i < KA) ? it[i] : 0ull;
    bool sel = (i < KA) && ((u32)(v >> 32) >= kth);
    u64 bal = __ballot(sel);
    u32 cnt = (u32)__popcll(bal);
    u32 base = 0;
    if (lane == 0 && cnt) base = atomicAdd(&sh_cnt, cnt);
    base = (u32)__shfl((int)base, 0, 64);
    if (sel) {
      u32 pos = base + (u32)__popcll(bal & ((1ull << lane) - 1ull));
      if (pos < 8192) arr[pos] = v;
    }
  }
  __syncthreads();
  u32 T = sh_cnt; if (T > 8192) T = 8192;
  for (int i = (int)T + tid; i < 8192; i += 1024) arr[i] = 0ull;

  // bitonic sort, descending; pair-indexed (4096 active pairs, no idle lanes)
  for (u32 k = 2; k <= 8192; k <<= 1) {
    for (u32 j = k >> 1; j > 0; j >>= 1) {
      __syncthreads();
#pragma unroll 4
      for (u32 m = tid; m < 4096; m += 1024) {
        u32 mm = m & (j - 1);
        u32 i = ((m - mm) << 1) + mm;
        u32 l = i + j;
        u64 a = arr[i], c = arr[l];
        bool dir = ((i & k) == 0);
        if ((a < c) == dir) { arr[i] = c; arr[l] = a; }
      }
    }
  }
  __syncthreads();
  for (int i = tid; i < N_PRE; i += 1024) {
    u64 v = arr[i];
    sitems[(size_t)b * N_PRE + i] = v;
    u32 kk = ~(u32)(v & 0xffffffffull);
    float4 bx = make_float4(0, 0, 0, 0);
    if (kk < KA) bx = roi[(size_t)b * KA + kk];
    sbox[(size_t)b * N_PRE + i] = bx;
  }
}

// ---------------- NMS suppression bitmask (upper-triangle 64x64 blocks) ----------------
__global__ __launch_bounds__(64) void k_mask(const float4* __restrict__ sbox,
    u64* __restrict__ mask, u64* __restrict__ diag) {
  const int cb = blockIdx.x, rb = blockIdx.y, b = blockIdx.z;
  if (cb < rb) return;
  const int tid = threadIdx.x;
  __shared__ float4 cbx[64];
  __shared__ float carea[64];
  int col0 = cb * 64;
  int c = col0 + tid;
  float4 v = (c < N_PRE) ? sbox[(size_t)b * N_PRE + c] : make_float4(0, 0, 0, 0);
  cbx[tid] = v;
  carea[tid] = (v.z - v.x) * (v.w - v.y);
  __syncthreads();
  int row = rb * 64 + tid;
  if (row >= N_PRE) return;
  float4 r = sbox[(size_t)b * N_PRE + row];
  float rarea = (r.z - r.x) * (r.w - r.y);
  u64 word = 0ull;
  for (int j = 0; j < 64; j++) {
    int cc = col0 + j;
    if (cc > row && cc < N_PRE) {
      float4 q = cbx[j];
      float ty = fmaxf(r.x, q.x), tx = fmaxf(r.y, q.y);
      float by = fminf(r.z, q.z), bx = fminf(r.w, q.w);
      float ihh = fmaxf(by - ty, 0.f), iww = fmaxf(bx - tx, 0.f);
      float inter = ihh * iww;
      float iou = inter / (rarea + carea[j] - inter + 1e-9f);
      if (iou > NMS_T) word |= (1ull << j);
    }
  }
  mask[((size_t)b * N_PRE + row) * NWORDS + cb] = word;
  if (cb == rb) diag[(size_t)b * N_PRE + row] = word;  // own-group suppression word
}

// ---------------- sequential NMS reduce (4-deep chained via diag) + outputs ----------------
__global__ __launch_bounds__(64) void k_nms_out(const u64* __restrict__ sitems,
    const float4* __restrict__ sbox, const u64* __restrict__ mask,
    const u64* __restrict__ diag, float* __restrict__ out) {
  const int b = blockIdx.x;
  const int lane = threadIdx.x;
  __shared__ u64 remv[NWORDS];
  __shared__ u64 pre[NWORDS];
  __shared__ u64 dia[N_PRE];
  __shared__ u32 keep[N_POST];
  for (int i = lane; i < NWORDS; i += 64) { remv[i] = 0ull; pre[i] = 0ull; }
  __syncthreads();
  u32 keyneg = ~__float_as_uint(NEGV);
  for (int i = lane; i < N_PRE; i += 64) {
    dia[i] = diag[(size_t)b * N_PRE + i];
    u32 key = (u32)(sitems[(size_t)b * N_PRE + i] >> 32);
    if (key == keyneg || key == 0u)
      atomicOr(&pre[i >> 6], 1ull << (i & 63));
  }
  if (lane == 0) pre[NWORDS - 1] |= ~((1ull << (N_PRE - 64 * (NWORDS - 1))) - 1ull);
  __syncthreads();

  int kc = 0;
  for (int g = 0; g < NWORDS && kc < N_POST; g++) {
    u64 done = 0ull;
    while (kc < N_POST) {
      u64 cur = remv[g] | pre[g] | done;
      if (cur == ~0ull) break;
      int r0 = -1, r1 = -1, r2 = -1, r3 = -1; int m = 1;
      u64 c2 = cur;
      int bit = __ffsll((long long)(~c2)) - 1;
      r0 = g * 64 + bit; c2 |= (1ull << bit) | dia[r0]; done |= 1ull << bit;
      if (c2 != ~0ull && kc + 1 < N_POST) {
        bit = __ffsll((long long)(~c2)) - 1;
        r1 = g * 64 + bit; c2 |= (1ull << bit) | dia[r1]; done |= 1ull << bit; m = 2;
        if (c2 != ~0ull && kc + 2 < N_POST) {
          bit = __ffsll((long long)(~c2)) - 1;
          r2 = g * 64 + bit; c2 |= (1ull << bit) | dia[r2]; done |= 1ull << bit; m = 3;
          if (c2 != ~0ull && kc + 3 < N_POST) {
            bit = __ffsll((long long)(~c2)) - 1;
            r3 = g * 64 + bit; c2 |= (1ull << bit) | dia[r3]; done |= 1ull << bit; m = 4;
          }
        }
      }
      if (lane == 0) {
        keep[kc] = (u32)r0;
        if (m > 1) keep[kc + 1] = (u32)r1;
        if (m > 2) keep[kc + 2] = (u32)r2;
        if (m > 3) keep[kc + 3] = (u32)r3;
      }
      int j = lane >> 4, l16 = lane & 15;
      int rj = (j == 0) ? r0 : (j == 1) ? r1 : (j == 2) ? r2 : r3;
      if (j < m) {
        const u64* mrow = mask + ((size_t)b * N_PRE + rj) * NWORDS;
        for (int cb = g + l16; cb < NWORDS; cb += 16)
          atomicOr(&remv[cb], mrow[cb]);
      }
      kc += m;
      __syncthreads();
    }
  }
  __syncthreads();
  for (int r = lane; r < N_POST; r += 64) {
    float4 bx = make_float4(0, 0, 0, 0);
    if (r < kc) bx = sbox[(size_t)b * N_PRE + keep[r]];
    ((float4*)out)[OFF_ROIS / 4 + (size_t)b * N_POST + r] = bx;
    out[OFF_RIDX + (size_t)b * N_POST + r] = (float)b;
  }
}

// ---------------- launch ----------------
extern "C" void kernel_launch(void* const* d_in, const int* in_sizes, int n_in,
                              void* d_out, int out_size, void* d_ws, size_t ws_size,
                              hipStream_t stream) {
  const float* x   = (const float*)d_in[0];
  const float* c1w = (const float*)d_in[1];
  const float* c1b = (const float*)d_in[2];
  const float* sw  = (const float*)d_in[3];
  const float* sb  = (const float*)d_in[4];
  const float* lw  = (const float*)d_in[5];
  const float* lb  = (const float*)d_in[6];
  const int* ih    = (const int*)d_in[7];
  const int* iw    = (const int*)d_in[8];
  float* out = (float*)d_out;
  char* wsb = (char*)d_ws;

  float* hid   = (float*)(wsb + WS_HID);
  float4* roi  = (float4*)(wsb + WS_ROI);
  u64* items   = (u64*)(wsb + WS_ITEMS);
  u64* sitems  = (u64*)(wsb + WS_SITEMS);
  float4* sbox = (float4*)(wsb + WS_SBOX);
  u64* maskp   = (u64*)(wsb + WS_MASK);
  u64* diagp   = (u64*)(wsb + WS_DIAG);
  float* wT3   = (float*)(wsb + WS_WT);

  // split-K degree chosen by available workspace (deterministic per session)
  int nsplit = 1;
  if (ws_size >= WS_PEXT + 3 * PART_BYTES) nsplit = 4;
  else if (ws_size >= WS_PEXT + 1 * PART_BYTES) nsplit = 2;
  float* p1 = (nsplit > 1) ? (float*)(wsb + WS_PEXT) : hid;
  float* p2 = (nsplit > 2) ? (float*)(wsb + WS_PEXT + PART_BYTES) : hid;
  float* p3 = (nsplit > 2) ? (float*)(wsb + WS_PEXT + 2 * PART_BYTES) : hid;

  hipLaunchKernelGGL(k_init, dim3(256, 8), dim3(64), 0, stream, c1w, wT3);
  hipLaunchKernelGGL(k_conv1, dim3(8, 50, 2 * nsplit), dim3(64), 0, stream,
                     x, wT3, hid, p1, p2, p3, 512 / nsplit);
  hipLaunchKernelGGL(k_combine, dim3(1050), dim3(256), 0, stream,
                     hid, p1, p2, p3, c1b, nsplit);
  hipLaunchKernelGGL(k_head, dim3(66), dim3(256), 0, stream,
                     hid, sw, sb, lw, lb, ih, iw, out, roi, items);
  hipLaunchKernelGGL(k_select, dim3(2), dim3(1024), 0, stream, items, roi, sitems, sbox);
  hipLaunchKernelGGL(k_mask, dim3(NWORDS, NWORDS, 2), dim3(64), 0, stream, sbox, maskp, diagp);
  hipLaunchKernelGGL(k_nms_out, dim3(2), dim3(64), 0, stream, sitems, sbox, maskp, diagp, out);
}